// Round 5
// baseline (516.651 us; speedup 1.0000x reference)
//
#include <hip/hip_runtime.h>
#include <hip/hip_bf16.h>
#include <math.h>

#define NNODES 100000
#define NEDGES 3200000
#define NBUK ((NNODES + 127) >> 7)   // 782 buckets of 128 nodes
#define NCHUNK 256
#define EPC (NEDGES / NCHUNK)        // 12500 edges per chunk

typedef float floatx2 __attribute__((ext_vector_type(2)));
typedef float f32x4 __attribute__((ext_vector_type(4)));
typedef short bf16x8 __attribute__((ext_vector_type(8)));

// ---- bf16 pack/unpack ----
__device__ __forceinline__ unsigned short f2bf(float x) {
    unsigned u = __float_as_uint(x);
    unsigned r = u + 0x7FFFu + ((u >> 16) & 1u);
    return (unsigned short)(r >> 16);
}

// ---- fp8 e4m3 packed accumulate (gfx950 HW converts) ----
__device__ __forceinline__ void acc16_fp8(uint4 v, floatx2* a) {
    a[0] += __builtin_amdgcn_cvt_pk_f32_fp8(v.x, false);
    a[1] += __builtin_amdgcn_cvt_pk_f32_fp8(v.x, true);
    a[2] += __builtin_amdgcn_cvt_pk_f32_fp8(v.y, false);
    a[3] += __builtin_amdgcn_cvt_pk_f32_fp8(v.y, true);
    a[4] += __builtin_amdgcn_cvt_pk_f32_fp8(v.z, false);
    a[5] += __builtin_amdgcn_cvt_pk_f32_fp8(v.z, true);
    a[6] += __builtin_amdgcn_cvt_pk_f32_fp8(v.w, false);
    a[7] += __builtin_amdgcn_cvt_pk_f32_fp8(v.w, true);
}

// ---------------- weight prep: Wt1[n][k]=bf16(W1[k][n]); Wt2[n][k]=bf16(W2[k][n]) ----------------
__global__ void prep_w_kernel(const float* __restrict__ W1, const float* __restrict__ W2,
                              unsigned short* __restrict__ Wt1, unsigned short* __restrict__ Wt2) {
    int i = blockIdx.x * 256 + threadIdx.x;
    if (i < 128 * 128) {
        int k = i >> 7, n = i & 127;        // coalesced read over n
        Wt1[n * 128 + k] = f2bf(W1[i]);
    } else if (i < 128 * 128 + 128 * 64) {
        int j = i - 128 * 128;
        int k = j >> 6, n = j & 63;
        Wt2[n * 128 + k] = f2bf(W2[j]);
    }
}

// ---------------- pass 1: per-chunk bucket histogram (LDS, int4 reads) ----------------
__global__ __launch_bounds__(1024) void chunk_hist_kernel(const int* __restrict__ dst,
                                                          int* __restrict__ hist) {
    __shared__ int h[NBUK];
    int c = blockIdx.x, t = threadIdx.x;
    for (int i = t; i < NBUK; i += 1024) h[i] = 0;
    __syncthreads();
    const int4* d4 = (const int4*)(dst + c * EPC);
    for (int i = t; i < EPC / 4; i += 1024) {
        int4 d = d4[i];
        atomicAdd(&h[d.x >> 7], 1);
        atomicAdd(&h[d.y >> 7], 1);
        atomicAdd(&h[d.z >> 7], 1);
        atomicAdd(&h[d.w >> 7], 1);
    }
    __syncthreads();
    for (int i = t; i < NBUK; i += 1024)
        hist[c * NBUK + i] = h[i];
}

// ---------------- pass 2: per-bucket exclusive prefix over chunks (parallel: 1 block/bucket) ----
__global__ __launch_bounds__(256) void col_scan_kernel(int* __restrict__ hist,
                                                       int* __restrict__ btot) {
    __shared__ int sdat[NCHUNK];
    int b = blockIdx.x;          // bucket
    int t = threadIdx.x;         // chunk (NCHUNK == 256 == blockDim)
    int v = hist[t * NBUK + b];
    sdat[t] = v;
    __syncthreads();
#pragma unroll
    for (int off = 1; off < NCHUNK; off <<= 1) {
        int x = (t >= off) ? sdat[t - off] : 0;
        __syncthreads();
        sdat[t] += x;
        __syncthreads();
    }
    hist[t * NBUK + b] = sdat[t] - v;     // exclusive prefix over chunks
    if (t == NCHUNK - 1) btot[b] = sdat[t];
}

// ---------------- pass 3: scan bucket totals -> bstart; zero small accumulators ----------------
__global__ void bucket_scan_kernel(const int* __restrict__ btot, int* __restrict__ bstart,
                                   int* __restrict__ row_start, float* __restrict__ smalls) {
    __shared__ int s[1024];
    int t = threadIdx.x;
    if (t < 592) smalls[t] = 0.0f;   // colsum(8) ata(64) ge(512)
    int v = (t < NBUK) ? btot[t] : 0;
    s[t] = v;
    __syncthreads();
    for (int off = 1; off < 1024; off <<= 1) {
        int x = (t >= off) ? s[t - off] : 0;
        __syncthreads();
        s[t] += x;
        __syncthreads();
    }
    if (t < NBUK) bstart[t] = s[t] - v;
    if (t == 0) {
        bstart[NBUK] = NEDGES;
        row_start[NNODES] = NEDGES;
    }
}

// ---------------- pass 4: deterministic scatter into bucket order (LDS cursors, int4 reads) ----
__global__ __launch_bounds__(1024) void chunk_scatter_kernel(const int* __restrict__ src,
                                                             const int* __restrict__ dst,
                                                             const int* __restrict__ hist,
                                                             const int* __restrict__ bstart,
                                                             int* __restrict__ ebuk) {
    __shared__ int cur[NBUK];
    int c = blockIdx.x, t = threadIdx.x;
    for (int i = t; i < NBUK; i += 1024)
        cur[i] = bstart[i] + hist[c * NBUK + i];
    __syncthreads();
    const int4* s4 = (const int4*)(src + c * EPC);
    const int4* d4 = (const int4*)(dst + c * EPC);
    for (int i = t; i < EPC / 4; i += 1024) {
        int4 s = s4[i];
        int4 d = d4[i];
        int p0 = atomicAdd(&cur[d.x >> 7], 1);
        ebuk[p0] = s.x | ((d.x & 127) << 20);
        int p1 = atomicAdd(&cur[d.y >> 7], 1);
        ebuk[p1] = s.y | ((d.y & 127) << 20);
        int p2 = atomicAdd(&cur[d.z >> 7], 1);
        ebuk[p2] = s.z | ((d.z & 127) << 20);
        int p3 = atomicAdd(&cur[d.w >> 7], 1);
        ebuk[p3] = s.w | ((d.w & 127) << 20);
    }
}

// ---------------- per-bucket: node counts, row_start, dinv, csr fill ----------------
__global__ __launch_bounds__(256) void build_kernel(const int* __restrict__ ebuk,
                                                    const int* __restrict__ bstart,
                                                    int* __restrict__ row_start,
                                                    float* __restrict__ dinv,
                                                    int* __restrict__ csr) {
    __shared__ int cnt[128];
    __shared__ int scn[128];
    __shared__ int cur[128];
    int b = blockIdx.x;
    int t = threadIdx.x;
    int s0 = bstart[b], s1 = bstart[b + 1];
    if (t < 128) cnt[t] = 0;
    __syncthreads();
    for (int i = s0 + t; i < s1; i += 256)
        atomicAdd(&cnt[(ebuk[i] >> 20) & 127], 1);
    __syncthreads();
    if (t < 128) scn[t] = cnt[t];
    __syncthreads();
#pragma unroll
    for (int off = 1; off < 128; off <<= 1) {
        int x = (t < 128 && t >= off) ? scn[t - off] : 0;
        __syncthreads();
        if (t < 128) scn[t] += x;
        __syncthreads();
    }
    int node = b * 128 + t;
    if (t < 128) {
        int rs = s0 + scn[t] - cnt[t];
        cur[t] = rs;
        if (node < NNODES) {
            row_start[node] = rs;
            dinv[node] = rsqrtf((float)cnt[t] + 1.0f);
        }
    }
    __syncthreads();
    for (int i = s0 + t; i < s1; i += 256) {
        int v = ebuk[i];
        int pos = atomicAdd(&cur[(v >> 20) & 127], 1);
        csr[pos] = v & 0xFFFFF;
    }
}

// ---------------- MFMA GEMM: stage(fp8) = rowscale * (A @ W) ----------------
// A: fp32 (ABF16=false) or bf16 (true), [N,KIN]; Wt: bf16 transposed [KOUT][KIN].
// 256 threads = 4 waves; 64-row tile; wave w handles rows w*16..w*16+15, all KOUT cols.
template <int KIN, int KOUT, bool ABF16>
__global__ __launch_bounds__(256) void gemm_mfma_kernel(const void* __restrict__ Av,
                                                        const unsigned short* __restrict__ Wt,
                                                        const float* __restrict__ rowscale,
                                                        unsigned char* __restrict__ stage) {
    constexpr int LDK = KIN + 8;          // bf16 elems; 16 B pad
    constexpr int LDC = KOUT + 4;         // fp32 elems
    constexpr int SH_AB = (64 + KOUT) * LDK * 2;
    constexpr int SH_C  = 64 * LDC * 4;
    constexpr int SH = SH_AB > SH_C ? SH_AB : SH_C;
    __shared__ char shbuf[SH];
    unsigned short* As = (unsigned short*)shbuf;       // [64][LDK]
    unsigned short* Ws = As + 64 * LDK;                // [KOUT][LDK]
    float* Cs = (float*)shbuf;                         // [64][LDC] (aliases, used after)
    int t = threadIdx.x;
    int block_row = blockIdx.x * 64;

    // stage Wt -> LDS (bf16, already transposed)
    for (int idx = t; idx < KOUT * (KIN / 8); idx += 256) {
        int n = idx / (KIN / 8), c = idx % (KIN / 8);
        *(uint4*)(Ws + n * LDK + c * 8) = *(const uint4*)(Wt + n * KIN + c * 8);
    }
    // stage A -> LDS (convert to bf16 if fp32)
    if (ABF16) {
        const unsigned short* A = (const unsigned short*)Av;
        for (int idx = t; idx < 64 * (KIN / 8); idx += 256) {
            int r = idx / (KIN / 8), c = idx % (KIN / 8);
            uint4 v = make_uint4(0, 0, 0, 0);
            if (block_row + r < NNODES)
                v = *(const uint4*)(A + (size_t)(block_row + r) * KIN + c * 8);
            *(uint4*)(As + r * LDK + c * 8) = v;
        }
    } else {
        const float* A = (const float*)Av;
        for (int idx = t; idx < 64 * (KIN / 4); idx += 256) {
            int r = idx / (KIN / 4), c = idx % (KIN / 4);
            float4 v = make_float4(0.f, 0.f, 0.f, 0.f);
            if (block_row + r < NNODES)
                v = *(const float4*)(A + (size_t)(block_row + r) * KIN + c * 4);
            unsigned p0 = (unsigned)f2bf(v.x) | ((unsigned)f2bf(v.y) << 16);
            unsigned p1 = (unsigned)f2bf(v.z) | ((unsigned)f2bf(v.w) << 16);
            *(uint2*)(As + r * LDK + c * 4) = make_uint2(p0, p1);
        }
    }
    __syncthreads();

    int wv = t >> 6, lane = t & 63;
    int r0 = wv * 16;
    int m = lane & 15, q = lane >> 4;     // A[m][k=q*8+j]; B[k=q*8+j][n=m]; C: col=m,row=q*4+reg
    constexpr int NT = KOUT / 16;
    constexpr int KS = KIN / 32;
    f32x4 acc[NT];
#pragma unroll
    for (int nt = 0; nt < NT; nt++) acc[nt] = (f32x4)(0.f);
    bf16x8 afr[KS];
#pragma unroll
    for (int ks = 0; ks < KS; ks++)
        afr[ks] = *(bf16x8*)(As + (r0 + m) * LDK + ks * 32 + q * 8);
#pragma unroll
    for (int nt = 0; nt < NT; nt++) {
#pragma unroll
        for (int ks = 0; ks < KS; ks++) {
            bf16x8 b = *(bf16x8*)(Ws + (nt * 16 + m) * LDK + ks * 32 + q * 8);
            acc[nt] = __builtin_amdgcn_mfma_f32_16x16x32_bf16(afr[ks], b, acc[nt], 0, 0, 0);
        }
    }
    __syncthreads();
    // C -> LDS (C/D layout: col=lane&15, row=(lane>>4)*4+reg)
#pragma unroll
    for (int nt = 0; nt < NT; nt++)
#pragma unroll
        for (int j = 0; j < 4; j++)
            Cs[(r0 + q * 4 + j) * LDC + nt * 16 + m] = acc[nt][j];
    __syncthreads();
    // epilogue: scale by dinv, fp8 pack, coalesced row-major store
    for (int idx = t; idx < 64 * (KOUT / 4); idx += 256) {
        int r = idx / (KOUT / 4), c4 = idx % (KOUT / 4);
        int row = block_row + r;
        if (row < NNODES) {
            float4 v = *(float4*)(Cs + r * LDC + c4 * 4);
            float d = rowscale[row];
            int pk = __builtin_amdgcn_cvt_pk_fp8_f32(v.x * d, v.y * d, 0, false);
            pk = __builtin_amdgcn_cvt_pk_fp8_f32(v.z * d, v.w * d, pk, true);
            *(unsigned*)(stage + (size_t)row * KOUT + c4 * 4) = (unsigned)pk;
        }
    }
}

// ---------------- gather K=128 fp8: 8 groups x 8 lanes x 16 B (uint4); 8-deep windows ----------
__global__ __launch_bounds__(256) void gather128_kernel(
    const unsigned char* __restrict__ hs, const int* __restrict__ row_start,
    const int* __restrict__ csr, const float* __restrict__ dinv,
    const float* __restrict__ bias, unsigned short* __restrict__ out) {
    int wave = threadIdx.x >> 6;
    int lane = threadIdx.x & 63;
    int n = blockIdx.x * 4 + wave;
    if (n >= NNODES) return;
    int g = lane >> 3;          // 0..7: edge sub-group
    int c = lane & 7;           // uint4 index within 128 B row
    unsigned boff = (unsigned)c << 4;
    int start = row_start[n], end = row_start[n + 1];
    floatx2 acc[8];
#pragma unroll
    for (int i = 0; i < 8; i++) acc[i] = (floatx2)(0.f);
    int w = (start + 3) & ~3;
    if (w > end) w = end;
    {   // head (<=3 edges): groups 0..2, one edge each
        int e2 = start + g;
        if (e2 < w) {
            unsigned o = ((unsigned)csr[e2] << 7) + boff;
            acc16_fp8(*(const uint4*)(hs + o), acc);
        }
    }
    // 64-edge windows: 8 groups x 8 contiguous edges, 8 uint4 gathers in flight per lane
    for (; w + 64 <= end; w += 64) {
        const int* cp = csr + w + 8 * g;
        int4 ca = *(const int4*)(cp);
        int4 cb = *(const int4*)(cp + 4);
        uint4 v0 = *(const uint4*)(hs + (((unsigned)ca.x << 7) + boff));
        uint4 v1 = *(const uint4*)(hs + (((unsigned)ca.y << 7) + boff));
        uint4 v2 = *(const uint4*)(hs + (((unsigned)ca.z << 7) + boff));
        uint4 v3 = *(const uint4*)(hs + (((unsigned)ca.w << 7) + boff));
        uint4 v4 = *(const uint4*)(hs + (((unsigned)cb.x << 7) + boff));
        uint4 v5 = *(const uint4*)(hs + (((unsigned)cb.y << 7) + boff));
        uint4 v6 = *(const uint4*)(hs + (((unsigned)cb.z << 7) + boff));
        uint4 v7 = *(const uint4*)(hs + (((unsigned)cb.w << 7) + boff));
        acc16_fp8(v0, acc); acc16_fp8(v1, acc); acc16_fp8(v2, acc); acc16_fp8(v3, acc);
        acc16_fp8(v4, acc); acc16_fp8(v5, acc); acc16_fp8(v6, acc); acc16_fp8(v7, acc);
    }
    // 16-edge windows: 2 edges per group
    for (; w + 16 <= end; w += 16) {
        int2 cs = *(const int2*)(csr + w + 2 * g);
        uint4 v0 = *(const uint4*)(hs + (((unsigned)cs.x << 7) + boff));
        uint4 v1 = *(const uint4*)(hs + (((unsigned)cs.y << 7) + boff));
        acc16_fp8(v0, acc); acc16_fp8(v1, acc);
    }
    for (int e2 = w + g; e2 < end; e2 += 8) {
        unsigned o = ((unsigned)csr[e2] << 7) + boff;
        acc16_fp8(*(const uint4*)(hs + o), acc);
    }
    // reduce across 8 edge-groups (lane bits 3..5)
#pragma unroll
    for (int off = 8; off <= 32; off <<= 1)
#pragma unroll
        for (int i = 0; i < 8; i++) {
            acc[i].x += __shfl_xor(acc[i].x, off);
            acc[i].y += __shfl_xor(acc[i].y, off);
        }
    if (g == 0) {
        floatx2 sf[8];
#pragma unroll
        for (int i = 0; i < 8; i++) sf[i] = (floatx2)(0.f);
        acc16_fp8(*(const uint4*)(hs + (((unsigned)n << 7) + boff)), sf);
        float d = dinv[n];
        int j = c * 16;
        float4 b0 = *(const float4*)(bias + j);
        float4 b1 = *(const float4*)(bias + j + 4);
        float4 b2 = *(const float4*)(bias + j + 8);
        float4 b3 = *(const float4*)(bias + j + 12);
        float r0  = fmaxf((acc[0].x + sf[0].x) * d + b0.x, 0.f);
        float r1  = fmaxf((acc[0].y + sf[0].y) * d + b0.y, 0.f);
        float r2  = fmaxf((acc[1].x + sf[1].x) * d + b0.z, 0.f);
        float r3  = fmaxf((acc[1].y + sf[1].y) * d + b0.w, 0.f);
        float r4  = fmaxf((acc[2].x + sf[2].x) * d + b1.x, 0.f);
        float r5  = fmaxf((acc[2].y + sf[2].y) * d + b1.y, 0.f);
        float r6  = fmaxf((acc[3].x + sf[3].x) * d + b1.z, 0.f);
        float r7  = fmaxf((acc[3].y + sf[3].y) * d + b1.w, 0.f);
        float r8  = fmaxf((acc[4].x + sf[4].x) * d + b2.x, 0.f);
        float r9  = fmaxf((acc[4].y + sf[4].y) * d + b2.y, 0.f);
        float r10 = fmaxf((acc[5].x + sf[5].x) * d + b2.z, 0.f);
        float r11 = fmaxf((acc[5].y + sf[5].y) * d + b2.w, 0.f);
        float r12 = fmaxf((acc[6].x + sf[6].x) * d + b3.x, 0.f);
        float r13 = fmaxf((acc[6].y + sf[6].y) * d + b3.y, 0.f);
        float r14 = fmaxf((acc[7].x + sf[7].x) * d + b3.z, 0.f);
        float r15 = fmaxf((acc[7].y + sf[7].y) * d + b3.w, 0.f);
        uint4 p0, p1;
        p0.x = (unsigned)f2bf(r0)  | ((unsigned)f2bf(r1)  << 16);
        p0.y = (unsigned)f2bf(r2)  | ((unsigned)f2bf(r3)  << 16);
        p0.z = (unsigned)f2bf(r4)  | ((unsigned)f2bf(r5)  << 16);
        p0.w = (unsigned)f2bf(r6)  | ((unsigned)f2bf(r7)  << 16);
        p1.x = (unsigned)f2bf(r8)  | ((unsigned)f2bf(r9)  << 16);
        p1.y = (unsigned)f2bf(r10) | ((unsigned)f2bf(r11) << 16);
        p1.z = (unsigned)f2bf(r12) | ((unsigned)f2bf(r13) << 16);
        p1.w = (unsigned)f2bf(r14) | ((unsigned)f2bf(r15) << 16);
        unsigned short* op = out + ((size_t)n << 7) + j;
        *(uint4*)op = p0;
        *(uint4*)(op + 8) = p1;
    }
}

// ---------------- gather K=64 fp8: 16 groups x 4 lanes x 16 B (uint4); 4-deep windows --------
__global__ __launch_bounds__(256) void gather64_kernel(
    const unsigned char* __restrict__ hs, const int* __restrict__ row_start,
    const int* __restrict__ csr, const float* __restrict__ dinv,
    const float* __restrict__ bias, float* __restrict__ out) {
    int wave = threadIdx.x >> 6;
    int lane = threadIdx.x & 63;
    int n = blockIdx.x * 4 + wave;
    if (n >= NNODES) return;
    int g = lane >> 2;          // 0..15: edge sub-group
    int c = lane & 3;           // uint4 index within 64 B row
    unsigned boff = (unsigned)c << 4;
    int start = row_start[n], end = row_start[n + 1];
    floatx2 acc[8];
#pragma unroll
    for (int i = 0; i < 8; i++) acc[i] = (floatx2)(0.f);
    int w = (start + 3) & ~3;
    if (w > end) w = end;
    {   // head (<=3 edges): groups 0..2, one edge each
        int e2 = start + g;
        if (e2 < w) {
            unsigned o = ((unsigned)csr[e2] << 6) + boff;
            acc16_fp8(*(const uint4*)(hs + o), acc);
        }
    }
    // 64-edge windows: 16 groups x 4 contiguous edges, 4 uint4 gathers in flight per lane
    for (; w + 64 <= end; w += 64) {
        int4 cs = *(const int4*)(csr + w + 4 * g);
        uint4 v0 = *(const uint4*)(hs + (((unsigned)cs.x << 6) + boff));
        uint4 v1 = *(const uint4*)(hs + (((unsigned)cs.y << 6) + boff));
        uint4 v2 = *(const uint4*)(hs + (((unsigned)cs.z << 6) + boff));
        uint4 v3 = *(const uint4*)(hs + (((unsigned)cs.w << 6) + boff));
        acc16_fp8(v0, acc); acc16_fp8(v1, acc); acc16_fp8(v2, acc); acc16_fp8(v3, acc);
    }
    // 16-edge windows: 1 edge per group
    for (; w + 16 <= end; w += 16) {
        unsigned o = ((unsigned)csr[w + g] << 6) + boff;
        acc16_fp8(*(const uint4*)(hs + o), acc);
    }
    for (int e2 = w + g; e2 < end; e2 += 16) {
        unsigned o = ((unsigned)csr[e2] << 6) + boff;
        acc16_fp8(*(const uint4*)(hs + o), acc);
    }
    // reduce across 16 edge-groups (lane bits 2..5)
#pragma unroll
    for (int off = 4; off <= 32; off <<= 1)
#pragma unroll
        for (int i = 0; i < 8; i++) {
            acc[i].x += __shfl_xor(acc[i].x, off);
            acc[i].y += __shfl_xor(acc[i].y, off);
        }
    if (g == 0) {
        floatx2 sf[8];
#pragma unroll
        for (int i = 0; i < 8; i++) sf[i] = (floatx2)(0.f);
        acc16_fp8(*(const uint4*)(hs + (((unsigned)n << 6) + boff)), sf);
        float d = dinv[n];
        int j = c * 16;
        float4 b0 = *(const float4*)(bias + j);
        float4 b1 = *(const float4*)(bias + j + 4);
        float4 b2 = *(const float4*)(bias + j + 8);
        float4 b3 = *(const float4*)(bias + j + 12);
        float4 o0, o1, o2, o3;
        o0.x = (acc[0].x + sf[0].x) * d + b0.x;
        o0.y = (acc[0].y + sf[0].y) * d + b0.y;
        o0.z = (acc[1].x + sf[1].x) * d + b0.z;
        o0.w = (acc[1].y + sf[1].y) * d + b0.w;
        o1.x = (acc[2].x + sf[2].x) * d + b1.x;
        o1.y = (acc[2].y + sf[2].y) * d + b1.y;
        o1.z = (acc[3].x + sf[3].x) * d + b1.z;
        o1.w = (acc[3].y + sf[3].y) * d + b1.w;
        o2.x = (acc[4].x + sf[4].x) * d + b2.x;
        o2.y = (acc[4].y + sf[4].y) * d + b2.y;
        o2.z = (acc[5].x + sf[5].x) * d + b2.z;
        o2.w = (acc[5].y + sf[5].y) * d + b2.w;
        o3.x = (acc[6].x + sf[6].x) * d + b3.x;
        o3.y = (acc[6].y + sf[6].y) * d + b3.y;
        o3.z = (acc[7].x + sf[7].x) * d + b3.z;
        o3.w = (acc[7].y + sf[7].y) * d + b3.w;
        float* op = out + ((size_t)n << 6) + j;
        *(float4*)op = o0;
        *(float4*)(op + 4) = o1;
        *(float4*)(op + 8) = o2;
        *(float4*)(op + 12) = o3;
    }
}

// ---------------- fused attention + pooling (grid-stride over 64-row tiles) ----------------
__global__ __launch_bounds__(256) void attnpool_kernel(const float* __restrict__ h2,
                                                       const float* __restrict__ Wf1,
                                                       const float* __restrict__ bf1,
                                                       const float* __restrict__ Wf2,
                                                       const float* __restrict__ bf2,
                                                       float* __restrict__ ge,
                                                       float* __restrict__ ata,
                                                       float* __restrict__ colsum) {
    __shared__ float h2S[64][68];
    __shared__ float a1S[64][68];
    __shared__ float attS[64][8];
    __shared__ float colS[8][64];
    int t = threadIdx.x;
    int d0 = t >> 6;
    int j  = t & 63;
    int de = t >> 3, ee = t & 7;
    float accge0 = 0.f, accge1 = 0.f, accata = 0.f, acccol = 0.f;
    int ntiles = (NNODES + 63) / 64;
    for (int tile = blockIdx.x; tile < ntiles; tile += gridDim.x) {
        int base = tile * 64;
#pragma unroll
        for (int q = 0; q < 4; q++) {
            int idx = t + q * 256;
            int r = idx >> 4, cc = (idx & 15) * 4;
            int row = base + r;
            float4 v = (row < NNODES) ? *(const float4*)(h2 + (size_t)row * 64 + cc)
                                      : make_float4(0.f, 0.f, 0.f, 0.f);
            *(float4*)(&h2S[r][cc]) = v;
        }
        __syncthreads();
        {
            int cg = t & 15, rg = t >> 4;
            int jj = cg * 4, r0 = rg * 4;
            float4 b4 = *(const float4*)(bf1 + jj);
            float4 acc[4];
#pragma unroll
            for (int r = 0; r < 4; r++) acc[r] = b4;
#pragma unroll 4
            for (int k = 0; k < 64; k++) {
                float4 wv = *(const float4*)(Wf1 + (size_t)k * 64 + jj);
#pragma unroll
                for (int r = 0; r < 4; r++) {
                    float a = h2S[r0 + r][k];
                    acc[r].x += a * wv.x; acc[r].y += a * wv.y;
                    acc[r].z += a * wv.z; acc[r].w += a * wv.w;
                }
            }
#pragma unroll
            for (int r = 0; r < 4; r++) {
                a1S[r0 + r][jj]     = tanhf(acc[r].x);
                a1S[r0 + r][jj + 1] = tanhf(acc[r].y);
                a1S[r0 + r][jj + 2] = tanhf(acc[r].z);
                a1S[r0 + r][jj + 3] = tanhf(acc[r].w);
            }
        }
        __syncthreads();
        {
            int cc = t & 7, r = t >> 3;
#pragma unroll
            for (int h = 0; h < 2; h++) {
                int rr = r + h * 32;
                float acc = bf2[cc];
                for (int k = 0; k < 64; k++)
                    acc += a1S[rr][k] * Wf2[(size_t)k * 8 + cc];
                float ev = (base + rr < NNODES) ? __expf(acc) : 0.f;
                attS[rr][cc] = ev;
                colS[cc][rr] = ev;
            }
        }
        __syncthreads();
#pragma unroll 8
        for (int i = 0; i < 64; i++) {
            float hv = h2S[i][j];
            accge0 += attS[i][d0] * hv;
            accge1 += attS[i][d0 + 4] * hv;
        }
        if (t < 64) {
#pragma unroll 8
            for (int i = 0; i < 64; i++) accata += attS[i][de] * attS[i][ee];
        }
        if (t < 8) {
            float s = 0.f;
#pragma unroll
            for (int r = 0; r < 64; r++) s += colS[t][r];
            acccol += s;
        }
        __syncthreads();
    }
    atomicAdd(ge + d0 * 64 + j, accge0);
    atomicAdd(ge + (d0 + 4) * 64 + j, accge1);
    if (t < 64) atomicAdd(ata + de * 8 + ee, accata);
    if (t < 8) atomicAdd(colsum + t, acccol);
}

// ---------------- tiny epilogue ----------------
__global__ void final_kernel(const float* __restrict__ geacc, const float* __restrict__ ata,
                             const float* __restrict__ colsum, const float* __restrict__ Wl,
                             const float* __restrict__ bl, float* __restrict__ out) {
    __shared__ float geF[512];
    __shared__ float inv[8];
    __shared__ float logits[10];
    int t = threadIdx.x;
    if (t < 8) inv[t] = 1.0f / colsum[t];
    __syncthreads();
    for (int idx = t; idx < 512; idx += 64) {
        int d = idx >> 6;
        float v = geacc[idx] * inv[d];
        geF[idx] = v;
        out[idx] = v;                       // graph_embedding
    }
    __syncthreads();
    if (t == 0) {
        float pen = 0.f;
        for (int d = 0; d < 8; d++) {
            float s = 0.f;
            for (int e = 0; e < 8; e++) {
                float p = ata[d * 8 + e] * inv[d] * inv[e] - (d == e ? 1.0f : 0.0f);
                s += p * p;
            }
            pen += sqrtf(s);
        }
        out[512] = pen;                     // penalty
    }
    if (t < 10) {
        float acc = bl[t];
        for (int k = 0; k < 512; k++) acc += geF[k] * Wl[(size_t)k * 10 + t];
        logits[t] = acc;
    }
    __syncthreads();
    if (t == 0) {
        float m = -INFINITY;
        for (int l = 0; l < 10; l++) m = fmaxf(m, logits[l]);
        float s = 0.f;
        for (int l = 0; l < 10; l++) s += expf(logits[l] - m);
        float ls = logf(s);
        for (int l = 0; l < 10; l++) out[513 + l] = logits[l] - m - ls;  // log_softmax
    }
}

extern "C" void kernel_launch(void* const* d_in, const int* in_sizes, int n_in,
                              void* d_out, int out_size, void* d_ws, size_t ws_size,
                              hipStream_t stream) {
    const int* esrc = (const int*)d_in[0];
    const int* edst = esrc + NEDGES;
    const float* X   = (const float*)d_in[1];
    const float* W1  = (const float*)d_in[2];
    const float* b1  = (const float*)d_in[3];
    const float* W2  = (const float*)d_in[4];
    const float* b2  = (const float*)d_in[5];
    const float* Wf1 = (const float*)d_in[6];
    const float* bf1 = (const float*)d_in[7];
    const float* Wf2 = (const float*)d_in[8];
    const float* bf2 = (const float*)d_in[9];
    const float* Wl  = (const float*)d_in[10];
    const float* bl  = (const float*)d_in[11];
    float* out = (float*)d_out;

    // workspace layout
    float* ws     = (float*)d_ws;
    float* dinv   = ws;                               // N (padded to 100352)
    float* smalls = ws + 100352;                      // 1024
    float* colsum = smalls + 8;                       // 8
    float* ata    = smalls + 16;                      // 64
    float* geacc  = smalls + 80;                      // 512
    float* A = ws + 101376;                           // N*128 fp32 region
    float* B = A + (size_t)NNODES * 128;              // N*128 fp32 region
    int* row_start = (int*)(B + (size_t)NNODES * 128);// N+1 (padded 100352)
    int* btot      = row_start + 100352;              // NBUK (padded 1024)
    int* bstart    = btot + 1024;                     // NBUK+1 (padded 1024)
    int* csr       = bstart + 1024;                   // E
    unsigned short* Wt1 = (unsigned short*)(csr + NEDGES);  // 128*128 bf16
    unsigned short* Wt2 = Wt1 + 128 * 128;                  // 64*128 bf16
    int* ebuk      = (int*)A;                         // E temp (consumed before gemm1 writes A)
    int* hist      = (int*)B;                         // NCHUNK*NBUK temp (consumed before gather writes B)
    unsigned char* stage = (unsigned char*)A;         // fp8 staging (N*128 or N*64 bytes)
    unsigned short* h1 = (unsigned short*)B;          // N*128 bf16
    float* h2  = B;                                   // N*64 fp32 (overwrites h1 after gemm2 consumed it)

    // ---- weight prep (bf16, transposed) ----
    prep_w_kernel<<<96, 256, 0, stream>>>(W1, W2, Wt1, Wt2);

    // ---- CSR build + dinv (deterministic two-pass counting sort) ----
    chunk_hist_kernel<<<NCHUNK, 1024, 0, stream>>>(edst, hist);
    col_scan_kernel<<<NBUK, 256, 0, stream>>>(hist, btot);
    bucket_scan_kernel<<<1, 1024, 0, stream>>>(btot, bstart, row_start, smalls);
    chunk_scatter_kernel<<<NCHUNK, 1024, 0, stream>>>(esrc, edst, hist, bstart, ebuk);
    build_kernel<<<NBUK, 256, 0, stream>>>(ebuk, bstart, row_start, dinv, csr);

    // ---- GCN layer 1: stage = fp8(dinv*(X@W1)) [MFMA]; h1(bf16) = relu(gather*dinv + b1) ----
    gemm_mfma_kernel<128, 128, false><<<(NNODES + 63) / 64, 256, 0, stream>>>(X, Wt1, dinv, stage);
    gather128_kernel<<<(NNODES + 3) / 4, 256, 0, stream>>>(stage, row_start, csr, dinv, b1, h1);

    // ---- GCN layer 2: stage = fp8(dinv*(h1@W2)) [MFMA]; h2 = gather*dinv + b2 ----
    gemm_mfma_kernel<128, 64, true><<<(NNODES + 63) / 64, 256, 0, stream>>>(h1, Wt2, dinv, stage);
    gather64_kernel<<<(NNODES + 3) / 4, 256, 0, stream>>>(stage, row_start, csr, dinv, b2, h2);

    // ---- fused attention + pooling ----
    attnpool_kernel<<<512, 256, 0, stream>>>(h2, Wf1, bf1, Wf2, bf2, geacc, ata, colsum);
    final_kernel<<<1, 64, 0, stream>>>(geacc, ata, colsum, Wl, bl, out);
}

// Round 6
// 506.905 us; speedup vs baseline: 1.0192x; 1.0192x over previous
//
#include <hip/hip_runtime.h>
#include <hip/hip_bf16.h>
#include <math.h>

#define NNODES 100000
#define NEDGES 3200000
#define NBUK ((NNODES + 127) >> 7)   // 782 buckets of 128 nodes
#define NCHUNK 256
#define EPC (NEDGES / NCHUNK)        // 12500 edges per chunk

typedef float floatx2 __attribute__((ext_vector_type(2)));
typedef float f32x4 __attribute__((ext_vector_type(4)));
typedef short bf16x8 __attribute__((ext_vector_type(8)));

// ---- bf16 pack/unpack ----
__device__ __forceinline__ unsigned short f2bf(float x) {
    unsigned u = __float_as_uint(x);
    unsigned r = u + 0x7FFFu + ((u >> 16) & 1u);
    return (unsigned short)(r >> 16);
}

// ---- fp8 e4m3 packed accumulate, 16 B at a time (gfx950 HW converts) ----
__device__ __forceinline__ void acc16_fp8(uint4 v, floatx2* a) {
    a[0] += __builtin_amdgcn_cvt_pk_f32_fp8(v.x, false);
    a[1] += __builtin_amdgcn_cvt_pk_f32_fp8(v.x, true);
    a[2] += __builtin_amdgcn_cvt_pk_f32_fp8(v.y, false);
    a[3] += __builtin_amdgcn_cvt_pk_f32_fp8(v.y, true);
    a[4] += __builtin_amdgcn_cvt_pk_f32_fp8(v.z, false);
    a[5] += __builtin_amdgcn_cvt_pk_f32_fp8(v.z, true);
    a[6] += __builtin_amdgcn_cvt_pk_f32_fp8(v.w, false);
    a[7] += __builtin_amdgcn_cvt_pk_f32_fp8(v.w, true);
}

// ---------------- weight prep: Wt1[n][k]=bf16(W1[k][n]); Wt2[n][k]=bf16(W2[k][n]) ----------------
__global__ void prep_w_kernel(const float* __restrict__ W1, const float* __restrict__ W2,
                              unsigned short* __restrict__ Wt1, unsigned short* __restrict__ Wt2) {
    int i = blockIdx.x * 256 + threadIdx.x;
    if (i < 128 * 128) {
        int k = i >> 7, n = i & 127;        // coalesced read over n
        Wt1[n * 128 + k] = f2bf(W1[i]);
    } else if (i < 128 * 128 + 128 * 64) {
        int j = i - 128 * 128;
        int k = j >> 6, n = j & 63;
        Wt2[n * 128 + k] = f2bf(W2[j]);
    }
}

// ---------------- pass 1: per-chunk bucket histogram (LDS, int4 reads) ----------------
__global__ __launch_bounds__(1024) void chunk_hist_kernel(const int* __restrict__ dst,
                                                          int* __restrict__ hist) {
    __shared__ int h[NBUK];
    int c = blockIdx.x, t = threadIdx.x;
    for (int i = t; i < NBUK; i += 1024) h[i] = 0;
    __syncthreads();
    const int4* d4 = (const int4*)(dst + c * EPC);
    for (int i = t; i < EPC / 4; i += 1024) {
        int4 d = d4[i];
        atomicAdd(&h[d.x >> 7], 1);
        atomicAdd(&h[d.y >> 7], 1);
        atomicAdd(&h[d.z >> 7], 1);
        atomicAdd(&h[d.w >> 7], 1);
    }
    __syncthreads();
    for (int i = t; i < NBUK; i += 1024)
        hist[c * NBUK + i] = h[i];
}

// ---------------- pass 2: per-bucket exclusive prefix over chunks (parallel: 1 block/bucket) ----
__global__ __launch_bounds__(256) void col_scan_kernel(int* __restrict__ hist,
                                                       int* __restrict__ btot) {
    __shared__ int sdat[NCHUNK];
    int b = blockIdx.x;          // bucket
    int t = threadIdx.x;         // chunk (NCHUNK == 256 == blockDim)
    int v = hist[t * NBUK + b];
    sdat[t] = v;
    __syncthreads();
#pragma unroll
    for (int off = 1; off < NCHUNK; off <<= 1) {
        int x = (t >= off) ? sdat[t - off] : 0;
        __syncthreads();
        sdat[t] += x;
        __syncthreads();
    }
    hist[t * NBUK + b] = sdat[t] - v;     // exclusive prefix over chunks
    if (t == NCHUNK - 1) btot[b] = sdat[t];
}

// ---------------- pass 3: scan bucket totals -> bstart; zero small accumulators ----------------
__global__ void bucket_scan_kernel(const int* __restrict__ btot, int* __restrict__ bstart,
                                   int* __restrict__ row_start, float* __restrict__ smalls) {
    __shared__ int s[1024];
    int t = threadIdx.x;
    if (t < 592) smalls[t] = 0.0f;   // colsum(8) ata(64) ge(512)
    int v = (t < NBUK) ? btot[t] : 0;
    s[t] = v;
    __syncthreads();
    for (int off = 1; off < 1024; off <<= 1) {
        int x = (t >= off) ? s[t - off] : 0;
        __syncthreads();
        s[t] += x;
        __syncthreads();
    }
    if (t < NBUK) bstart[t] = s[t] - v;
    if (t == 0) {
        bstart[NBUK] = NEDGES;
        row_start[NNODES] = NEDGES;
    }
}

// ---------------- pass 4: deterministic scatter into bucket order (LDS cursors, int4 reads) ----
__global__ __launch_bounds__(1024) void chunk_scatter_kernel(const int* __restrict__ src,
                                                             const int* __restrict__ dst,
                                                             const int* __restrict__ hist,
                                                             const int* __restrict__ bstart,
                                                             int* __restrict__ ebuk) {
    __shared__ int cur[NBUK];
    int c = blockIdx.x, t = threadIdx.x;
    for (int i = t; i < NBUK; i += 1024)
        cur[i] = bstart[i] + hist[c * NBUK + i];
    __syncthreads();
    const int4* s4 = (const int4*)(src + c * EPC);
    const int4* d4 = (const int4*)(dst + c * EPC);
    for (int i = t; i < EPC / 4; i += 1024) {
        int4 s = s4[i];
        int4 d = d4[i];
        int p0 = atomicAdd(&cur[d.x >> 7], 1);
        ebuk[p0] = s.x | ((d.x & 127) << 20);
        int p1 = atomicAdd(&cur[d.y >> 7], 1);
        ebuk[p1] = s.y | ((d.y & 127) << 20);
        int p2 = atomicAdd(&cur[d.z >> 7], 1);
        ebuk[p2] = s.z | ((d.z & 127) << 20);
        int p3 = atomicAdd(&cur[d.w >> 7], 1);
        ebuk[p3] = s.w | ((d.w & 127) << 20);
    }
}

// ---------------- per-bucket: node counts, row_start, dinv, csr fill ----------------
__global__ __launch_bounds__(256) void build_kernel(const int* __restrict__ ebuk,
                                                    const int* __restrict__ bstart,
                                                    int* __restrict__ row_start,
                                                    float* __restrict__ dinv,
                                                    int* __restrict__ csr) {
    __shared__ int cnt[128];
    __shared__ int scn[128];
    __shared__ int cur[128];
    int b = blockIdx.x;
    int t = threadIdx.x;
    int s0 = bstart[b], s1 = bstart[b + 1];
    if (t < 128) cnt[t] = 0;
    __syncthreads();
    for (int i = s0 + t; i < s1; i += 256)
        atomicAdd(&cnt[(ebuk[i] >> 20) & 127], 1);
    __syncthreads();
    if (t < 128) scn[t] = cnt[t];
    __syncthreads();
#pragma unroll
    for (int off = 1; off < 128; off <<= 1) {
        int x = (t < 128 && t >= off) ? scn[t - off] : 0;
        __syncthreads();
        if (t < 128) scn[t] += x;
        __syncthreads();
    }
    int node = b * 128 + t;
    if (t < 128) {
        int rs = s0 + scn[t] - cnt[t];
        cur[t] = rs;
        if (node < NNODES) {
            row_start[node] = rs;
            dinv[node] = rsqrtf((float)cnt[t] + 1.0f);
        }
    }
    __syncthreads();
    for (int i = s0 + t; i < s1; i += 256) {
        int v = ebuk[i];
        int pos = atomicAdd(&cur[(v >> 20) & 127], 1);
        csr[pos] = v & 0xFFFFF;
    }
}

// ---------------- MFMA GEMM: stage(fp8) = rowscale * (A @ W) ----------------
// A: fp32 (ABF16=false) or bf16 (true), [N,KIN]; Wt: bf16 transposed [KOUT][KIN].
// 256 threads = 4 waves; 64-row tile; wave w handles rows w*16..w*16+15, all KOUT cols.
template <int KIN, int KOUT, bool ABF16>
__global__ __launch_bounds__(256) void gemm_mfma_kernel(const void* __restrict__ Av,
                                                        const unsigned short* __restrict__ Wt,
                                                        const float* __restrict__ rowscale,
                                                        unsigned char* __restrict__ stage) {
    constexpr int LDK = KIN + 8;          // bf16 elems; 16 B pad
    constexpr int LDC = KOUT + 4;         // fp32 elems
    constexpr int SH_AB = (64 + KOUT) * LDK * 2;
    constexpr int SH_C  = 64 * LDC * 4;
    constexpr int SH = SH_AB > SH_C ? SH_AB : SH_C;
    __shared__ char shbuf[SH];
    unsigned short* As = (unsigned short*)shbuf;       // [64][LDK]
    unsigned short* Ws = As + 64 * LDK;                // [KOUT][LDK]
    float* Cs = (float*)shbuf;                         // [64][LDC] (aliases, used after)
    int t = threadIdx.x;
    int block_row = blockIdx.x * 64;

    // stage Wt -> LDS (bf16, already transposed)
    for (int idx = t; idx < KOUT * (KIN / 8); idx += 256) {
        int n = idx / (KIN / 8), c = idx % (KIN / 8);
        *(uint4*)(Ws + n * LDK + c * 8) = *(const uint4*)(Wt + n * KIN + c * 8);
    }
    // stage A -> LDS (convert to bf16 if fp32)
    if (ABF16) {
        const unsigned short* A = (const unsigned short*)Av;
        for (int idx = t; idx < 64 * (KIN / 8); idx += 256) {
            int r = idx / (KIN / 8), c = idx % (KIN / 8);
            uint4 v = make_uint4(0, 0, 0, 0);
            if (block_row + r < NNODES)
                v = *(const uint4*)(A + (size_t)(block_row + r) * KIN + c * 8);
            *(uint4*)(As + r * LDK + c * 8) = v;
        }
    } else {
        const float* A = (const float*)Av;
        for (int idx = t; idx < 64 * (KIN / 4); idx += 256) {
            int r = idx / (KIN / 4), c = idx % (KIN / 4);
            float4 v = make_float4(0.f, 0.f, 0.f, 0.f);
            if (block_row + r < NNODES)
                v = *(const float4*)(A + (size_t)(block_row + r) * KIN + c * 4);
            unsigned p0 = (unsigned)f2bf(v.x) | ((unsigned)f2bf(v.y) << 16);
            unsigned p1 = (unsigned)f2bf(v.z) | ((unsigned)f2bf(v.w) << 16);
            *(uint2*)(As + r * LDK + c * 4) = make_uint2(p0, p1);
        }
    }
    __syncthreads();

    int wv = t >> 6, lane = t & 63;
    int r0 = wv * 16;
    int m = lane & 15, q = lane >> 4;     // A[m][k=q*8+j]; B[k=q*8+j][n=m]; C: col=m,row=q*4+reg
    constexpr int NT = KOUT / 16;
    constexpr int KS = KIN / 32;
    f32x4 acc[NT];
#pragma unroll
    for (int nt = 0; nt < NT; nt++) acc[nt] = (f32x4)(0.f);
    bf16x8 afr[KS];
#pragma unroll
    for (int ks = 0; ks < KS; ks++)
        afr[ks] = *(bf16x8*)(As + (r0 + m) * LDK + ks * 32 + q * 8);
#pragma unroll
    for (int nt = 0; nt < NT; nt++) {
#pragma unroll
        for (int ks = 0; ks < KS; ks++) {
            bf16x8 b = *(bf16x8*)(Ws + (nt * 16 + m) * LDK + ks * 32 + q * 8);
            acc[nt] = __builtin_amdgcn_mfma_f32_16x16x32_bf16(afr[ks], b, acc[nt], 0, 0, 0);
        }
    }
    __syncthreads();
    // C -> LDS (C/D layout: col=lane&15, row=(lane>>4)*4+reg)
#pragma unroll
    for (int nt = 0; nt < NT; nt++)
#pragma unroll
        for (int j = 0; j < 4; j++)
            Cs[(r0 + q * 4 + j) * LDC + nt * 16 + m] = acc[nt][j];
    __syncthreads();
    // epilogue: scale by dinv, fp8 pack, coalesced row-major store
    for (int idx = t; idx < 64 * (KOUT / 4); idx += 256) {
        int r = idx / (KOUT / 4), c4 = idx % (KOUT / 4);
        int row = block_row + r;
        if (row < NNODES) {
            float4 v = *(float4*)(Cs + r * LDC + c4 * 4);
            float d = rowscale[row];
            int pk = __builtin_amdgcn_cvt_pk_fp8_f32(v.x * d, v.y * d, 0, false);
            pk = __builtin_amdgcn_cvt_pk_fp8_f32(v.z * d, v.w * d, pk, true);
            *(unsigned*)(stage + (size_t)row * KOUT + c4 * 4) = (unsigned)pk;
        }
    }
}

// ---------------- gather K=128 fp8: 8 groups x 8 lanes x 16 B (uint4); 32-edge windows ----------
// Depth-4 per lane (16 data VGPRs); launch_bounds(256,8) pins VGPR<=64 for full occupancy.
__global__ __launch_bounds__(256, 8) void gather128_kernel(
    const unsigned char* __restrict__ hs, const int* __restrict__ row_start,
    const int* __restrict__ csr, const float* __restrict__ dinv,
    const float* __restrict__ bias, unsigned short* __restrict__ out) {
    int wave = threadIdx.x >> 6;
    int lane = threadIdx.x & 63;
    int n = blockIdx.x * 4 + wave;
    if (n >= NNODES) return;
    int g = lane >> 3;          // 0..7: edge sub-group
    int c = lane & 7;           // uint4 index within 128 B row
    unsigned boff = (unsigned)c << 4;
    int start = row_start[n], end = row_start[n + 1];
    floatx2 acc[8];
#pragma unroll
    for (int i = 0; i < 8; i++) acc[i] = (floatx2)(0.f);
    int w = (start + 3) & ~3;
    if (w > end) w = end;
    {   // head (<=3 edges): groups 0..2, one edge each
        int e2 = start + g;
        if (e2 < w) {
            unsigned o = ((unsigned)csr[e2] << 7) + boff;
            acc16_fp8(*(const uint4*)(hs + o), acc);
        }
    }
    // 32-edge windows: 8 groups x 4 contiguous edges, 4 uint4 gathers in flight per lane
    for (; w + 32 <= end; w += 32) {
        int4 cs = *(const int4*)(csr + w + 4 * g);
        uint4 v0 = *(const uint4*)(hs + (((unsigned)cs.x << 7) + boff));
        uint4 v1 = *(const uint4*)(hs + (((unsigned)cs.y << 7) + boff));
        uint4 v2 = *(const uint4*)(hs + (((unsigned)cs.z << 7) + boff));
        uint4 v3 = *(const uint4*)(hs + (((unsigned)cs.w << 7) + boff));
        acc16_fp8(v0, acc); acc16_fp8(v1, acc); acc16_fp8(v2, acc); acc16_fp8(v3, acc);
    }
    // tail: 1 edge per group per round (8 edges/round)
    for (int e2 = w + g; e2 < end; e2 += 8) {
        unsigned o = ((unsigned)csr[e2] << 7) + boff;
        acc16_fp8(*(const uint4*)(hs + o), acc);
    }
    // reduce across 8 edge-groups (lane bits 3..5)
#pragma unroll
    for (int off = 8; off <= 32; off <<= 1)
#pragma unroll
        for (int i = 0; i < 8; i++) {
            acc[i].x += __shfl_xor(acc[i].x, off);
            acc[i].y += __shfl_xor(acc[i].y, off);
        }
    if (g == 0) {
        floatx2 sf[8];
#pragma unroll
        for (int i = 0; i < 8; i++) sf[i] = (floatx2)(0.f);
        acc16_fp8(*(const uint4*)(hs + (((unsigned)n << 7) + boff)), sf);
        float d = dinv[n];
        int j = c * 16;
        float4 b0 = *(const float4*)(bias + j);
        float4 b1 = *(const float4*)(bias + j + 4);
        float4 b2 = *(const float4*)(bias + j + 8);
        float4 b3 = *(const float4*)(bias + j + 12);
        float r0  = fmaxf((acc[0].x + sf[0].x) * d + b0.x, 0.f);
        float r1  = fmaxf((acc[0].y + sf[0].y) * d + b0.y, 0.f);
        float r2  = fmaxf((acc[1].x + sf[1].x) * d + b0.z, 0.f);
        float r3  = fmaxf((acc[1].y + sf[1].y) * d + b0.w, 0.f);
        float r4  = fmaxf((acc[2].x + sf[2].x) * d + b1.x, 0.f);
        float r5  = fmaxf((acc[2].y + sf[2].y) * d + b1.y, 0.f);
        float r6  = fmaxf((acc[3].x + sf[3].x) * d + b1.z, 0.f);
        float r7  = fmaxf((acc[3].y + sf[3].y) * d + b1.w, 0.f);
        float r8  = fmaxf((acc[4].x + sf[4].x) * d + b2.x, 0.f);
        float r9  = fmaxf((acc[4].y + sf[4].y) * d + b2.y, 0.f);
        float r10 = fmaxf((acc[5].x + sf[5].x) * d + b2.z, 0.f);
        float r11 = fmaxf((acc[5].y + sf[5].y) * d + b2.w, 0.f);
        float r12 = fmaxf((acc[6].x + sf[6].x) * d + b3.x, 0.f);
        float r13 = fmaxf((acc[6].y + sf[6].y) * d + b3.y, 0.f);
        float r14 = fmaxf((acc[7].x + sf[7].x) * d + b3.z, 0.f);
        float r15 = fmaxf((acc[7].y + sf[7].y) * d + b3.w, 0.f);
        uint4 p0, p1;
        p0.x = (unsigned)f2bf(r0)  | ((unsigned)f2bf(r1)  << 16);
        p0.y = (unsigned)f2bf(r2)  | ((unsigned)f2bf(r3)  << 16);
        p0.z = (unsigned)f2bf(r4)  | ((unsigned)f2bf(r5)  << 16);
        p0.w = (unsigned)f2bf(r6)  | ((unsigned)f2bf(r7)  << 16);
        p1.x = (unsigned)f2bf(r8)  | ((unsigned)f2bf(r9)  << 16);
        p1.y = (unsigned)f2bf(r10) | ((unsigned)f2bf(r11) << 16);
        p1.z = (unsigned)f2bf(r12) | ((unsigned)f2bf(r13) << 16);
        p1.w = (unsigned)f2bf(r14) | ((unsigned)f2bf(r15) << 16);
        unsigned short* op = out + ((size_t)n << 7) + j;
        *(uint4*)op = p0;
        *(uint4*)(op + 8) = p1;
    }
}

// ---------------- gather K=64 fp8: 16 groups x 4 lanes x 16 B (uint4); 32-edge windows --------
// Depth-2 per lane (8 data VGPRs); launch_bounds(256,8) pins VGPR<=64.
__global__ __launch_bounds__(256, 8) void gather64_kernel(
    const unsigned char* __restrict__ hs, const int* __restrict__ row_start,
    const int* __restrict__ csr, const float* __restrict__ dinv,
    const float* __restrict__ bias, float* __restrict__ out) {
    int wave = threadIdx.x >> 6;
    int lane = threadIdx.x & 63;
    int n = blockIdx.x * 4 + wave;
    if (n >= NNODES) return;
    int g = lane >> 2;          // 0..15: edge sub-group
    int c = lane & 3;           // uint4 index within 64 B row
    unsigned boff = (unsigned)c << 4;
    int start = row_start[n], end = row_start[n + 1];
    floatx2 acc[8];
#pragma unroll
    for (int i = 0; i < 8; i++) acc[i] = (floatx2)(0.f);
    int w = (start + 1) & ~1;
    if (w > end) w = end;
    {   // head (<=1 edge): group 0
        if (start < w && g == 0) {
            unsigned o = ((unsigned)csr[start] << 6) + boff;
            acc16_fp8(*(const uint4*)(hs + o), acc);
        }
    }
    // 32-edge windows: 16 groups x 2 contiguous edges, 2 uint4 gathers in flight per lane
    for (; w + 32 <= end; w += 32) {
        int2 cs = *(const int2*)(csr + w + 2 * g);
        uint4 v0 = *(const uint4*)(hs + (((unsigned)cs.x << 6) + boff));
        uint4 v1 = *(const uint4*)(hs + (((unsigned)cs.y << 6) + boff));
        acc16_fp8(v0, acc); acc16_fp8(v1, acc);
    }
    // tail: 1 edge per group per round (16 edges/round)
    for (int e2 = w + g; e2 < end; e2 += 16) {
        unsigned o = ((unsigned)csr[e2] << 6) + boff;
        acc16_fp8(*(const uint4*)(hs + o), acc);
    }
    // reduce across 16 edge-groups (lane bits 2..5)
#pragma unroll
    for (int off = 4; off <= 32; off <<= 1)
#pragma unroll
        for (int i = 0; i < 8; i++) {
            acc[i].x += __shfl_xor(acc[i].x, off);
            acc[i].y += __shfl_xor(acc[i].y, off);
        }
    if (g == 0) {
        floatx2 sf[8];
#pragma unroll
        for (int i = 0; i < 8; i++) sf[i] = (floatx2)(0.f);
        acc16_fp8(*(const uint4*)(hs + (((unsigned)n << 6) + boff)), sf);
        float d = dinv[n];
        int j = c * 16;
        float4 b0 = *(const float4*)(bias + j);
        float4 b1 = *(const float4*)(bias + j + 4);
        float4 b2 = *(const float4*)(bias + j + 8);
        float4 b3 = *(const float4*)(bias + j + 12);
        float4 o0, o1, o2, o3;
        o0.x = (acc[0].x + sf[0].x) * d + b0.x;
        o0.y = (acc[0].y + sf[0].y) * d + b0.y;
        o0.z = (acc[1].x + sf[1].x) * d + b0.z;
        o0.w = (acc[1].y + sf[1].y) * d + b0.w;
        o1.x = (acc[2].x + sf[2].x) * d + b1.x;
        o1.y = (acc[2].y + sf[2].y) * d + b1.y;
        o1.z = (acc[3].x + sf[3].x) * d + b1.z;
        o1.w = (acc[3].y + sf[3].y) * d + b1.w;
        o2.x = (acc[4].x + sf[4].x) * d + b2.x;
        o2.y = (acc[4].y + sf[4].y) * d + b2.y;
        o2.z = (acc[5].x + sf[5].x) * d + b2.z;
        o2.w = (acc[5].y + sf[5].y) * d + b2.w;
        o3.x = (acc[6].x + sf[6].x) * d + b3.x;
        o3.y = (acc[6].y + sf[6].y) * d + b3.y;
        o3.z = (acc[7].x + sf[7].x) * d + b3.z;
        o3.w = (acc[7].y + sf[7].y) * d + b3.w;
        float* op = out + ((size_t)n << 6) + j;
        *(float4*)op = o0;
        *(float4*)(op + 4) = o1;
        *(float4*)(op + 8) = o2;
        *(float4*)(op + 12) = o3;
    }
}

// ---------------- fused attention + pooling (grid-stride over 64-row tiles) ----------------
__global__ __launch_bounds__(256) void attnpool_kernel(const float* __restrict__ h2,
                                                       const float* __restrict__ Wf1,
                                                       const float* __restrict__ bf1,
                                                       const float* __restrict__ Wf2,
                                                       const float* __restrict__ bf2,
                                                       float* __restrict__ ge,
                                                       float* __restrict__ ata,
                                                       float* __restrict__ colsum) {
    __shared__ float h2S[64][68];
    __shared__ float a1S[64][68];
    __shared__ float attS[64][8];
    __shared__ float colS[8][64];
    int t = threadIdx.x;
    int d0 = t >> 6;
    int j  = t & 63;
    int de = t >> 3, ee = t & 7;
    float accge0 = 0.f, accge1 = 0.f, accata = 0.f, acccol = 0.f;
    int ntiles = (NNODES + 63) / 64;
    for (int tile = blockIdx.x; tile < ntiles; tile += gridDim.x) {
        int base = tile * 64;
#pragma unroll
        for (int q = 0; q < 4; q++) {
            int idx = t + q * 256;
            int r = idx >> 4, cc = (idx & 15) * 4;
            int row = base + r;
            float4 v = (row < NNODES) ? *(const float4*)(h2 + (size_t)row * 64 + cc)
                                      : make_float4(0.f, 0.f, 0.f, 0.f);
            *(float4*)(&h2S[r][cc]) = v;
        }
        __syncthreads();
        {
            int cg = t & 15, rg = t >> 4;
            int jj = cg * 4, r0 = rg * 4;
            float4 b4 = *(const float4*)(bf1 + jj);
            float4 acc[4];
#pragma unroll
            for (int r = 0; r < 4; r++) acc[r] = b4;
#pragma unroll 4
            for (int k = 0; k < 64; k++) {
                float4 wv = *(const float4*)(Wf1 + (size_t)k * 64 + jj);
#pragma unroll
                for (int r = 0; r < 4; r++) {
                    float a = h2S[r0 + r][k];
                    acc[r].x += a * wv.x; acc[r].y += a * wv.y;
                    acc[r].z += a * wv.z; acc[r].w += a * wv.w;
                }
            }
#pragma unroll
            for (int r = 0; r < 4; r++) {
                a1S[r0 + r][jj]     = tanhf(acc[r].x);
                a1S[r0 + r][jj + 1] = tanhf(acc[r].y);
                a1S[r0 + r][jj + 2] = tanhf(acc[r].z);
                a1S[r0 + r][jj + 3] = tanhf(acc[r].w);
            }
        }
        __syncthreads();
        {
            int cc = t & 7, r = t >> 3;
#pragma unroll
            for (int h = 0; h < 2; h++) {
                int rr = r + h * 32;
                float acc = bf2[cc];
                for (int k = 0; k < 64; k++)
                    acc += a1S[rr][k] * Wf2[(size_t)k * 8 + cc];
                float ev = (base + rr < NNODES) ? __expf(acc) : 0.f;
                attS[rr][cc] = ev;
                colS[cc][rr] = ev;
            }
        }
        __syncthreads();
#pragma unroll 8
        for (int i = 0; i < 64; i++) {
            float hv = h2S[i][j];
            accge0 += attS[i][d0] * hv;
            accge1 += attS[i][d0 + 4] * hv;
        }
        if (t < 64) {
#pragma unroll 8
            for (int i = 0; i < 64; i++) accata += attS[i][de] * attS[i][ee];
        }
        if (t < 8) {
            float s = 0.f;
#pragma unroll
            for (int r = 0; r < 64; r++) s += colS[t][r];
            acccol += s;
        }
        __syncthreads();
    }
    atomicAdd(ge + d0 * 64 + j, accge0);
    atomicAdd(ge + (d0 + 4) * 64 + j, accge1);
    if (t < 64) atomicAdd(ata + de * 8 + ee, accata);
    if (t < 8) atomicAdd(colsum + t, acccol);
}

// ---------------- tiny epilogue ----------------
__global__ void final_kernel(const float* __restrict__ geacc, const float* __restrict__ ata,
                             const float* __restrict__ colsum, const float* __restrict__ Wl,
                             const float* __restrict__ bl, float* __restrict__ out) {
    __shared__ float geF[512];
    __shared__ float inv[8];
    __shared__ float logits[10];
    int t = threadIdx.x;
    if (t < 8) inv[t] = 1.0f / colsum[t];
    __syncthreads();
    for (int idx = t; idx < 512; idx += 64) {
        int d = idx >> 6;
        float v = geacc[idx] * inv[d];
        geF[idx] = v;
        out[idx] = v;                       // graph_embedding
    }
    __syncthreads();
    if (t == 0) {
        float pen = 0.f;
        for (int d = 0; d < 8; d++) {
            float s = 0.f;
            for (int e = 0; e < 8; e++) {
                float p = ata[d * 8 + e] * inv[d] * inv[e] - (d == e ? 1.0f : 0.0f);
                s += p * p;
            }
            pen += sqrtf(s);
        }
        out[512] = pen;                     // penalty
    }
    if (t < 10) {
        float acc = bl[t];
        for (int k = 0; k < 512; k++) acc += geF[k] * Wl[(size_t)k * 10 + t];
        logits[t] = acc;
    }
    __syncthreads();
    if (t == 0) {
        float m = -INFINITY;
        for (int l = 0; l < 10; l++) m = fmaxf(m, logits[l]);
        float s = 0.f;
        for (int l = 0; l < 10; l++) s += expf(logits[l] - m);
        float ls = logf(s);
        for (int l = 0; l < 10; l++) out[513 + l] = logits[l] - m - ls;  // log_softmax
    }
}

extern "C" void kernel_launch(void* const* d_in, const int* in_sizes, int n_in,
                              void* d_out, int out_size, void* d_ws, size_t ws_size,
                              hipStream_t stream) {
    const int* esrc = (const int*)d_in[0];
    const int* edst = esrc + NEDGES;
    const float* X   = (const float*)d_in[1];
    const float* W1  = (const float*)d_in[2];
    const float* b1  = (const float*)d_in[3];
    const float* W2  = (const float*)d_in[4];
    const float* b2  = (const float*)d_in[5];
    const float* Wf1 = (const float*)d_in[6];
    const float* bf1 = (const float*)d_in[7];
    const float* Wf2 = (const float*)d_in[8];
    const float* bf2 = (const float*)d_in[9];
    const float* Wl  = (const float*)d_in[10];
    const float* bl  = (const float*)d_in[11];
    float* out = (float*)d_out;

    // workspace layout
    float* ws     = (float*)d_ws;
    float* dinv   = ws;                               // N (padded to 100352)
    float* smalls = ws + 100352;                      // 1024
    float* colsum = smalls + 8;                       // 8
    float* ata    = smalls + 16;                      // 64
    float* geacc  = smalls + 80;                      // 512
    float* A = ws + 101376;                           // N*128 fp32 region
    float* B = A + (size_t)NNODES * 128;              // N*128 fp32 region
    int* row_start = (int*)(B + (size_t)NNODES * 128);// N+1 (padded 100352)
    int* btot      = row_start + 100352;              // NBUK (padded 1024)
    int* bstart    = btot + 1024;                     // NBUK+1 (padded 1024)
    int* csr       = bstart + 1024;                   // E
    unsigned short* Wt1 = (unsigned short*)(csr + NEDGES);  // 128*128 bf16
    unsigned short* Wt2 = Wt1 + 128 * 128;                  // 64*128 bf16
    int* ebuk      = (int*)A;                         // E temp (consumed before gemm1 writes A)
    int* hist      = (int*)B;                         // NCHUNK*NBUK temp (consumed before gather writes B)
    unsigned char* stage = (unsigned char*)A;         // fp8 staging (N*128 or N*64 bytes)
    unsigned short* h1 = (unsigned short*)B;          // N*128 bf16
    float* h2  = B;                                   // N*64 fp32 (overwrites h1 after gemm2 consumed it)

    // ---- weight prep (bf16, transposed) ----
    prep_w_kernel<<<96, 256, 0, stream>>>(W1, W2, Wt1, Wt2);

    // ---- CSR build + dinv (deterministic two-pass counting sort) ----
    chunk_hist_kernel<<<NCHUNK, 1024, 0, stream>>>(edst, hist);
    col_scan_kernel<<<NBUK, 256, 0, stream>>>(hist, btot);
    bucket_scan_kernel<<<1, 1024, 0, stream>>>(btot, bstart, row_start, smalls);
    chunk_scatter_kernel<<<NCHUNK, 1024, 0, stream>>>(esrc, edst, hist, bstart, ebuk);
    build_kernel<<<NBUK, 256, 0, stream>>>(ebuk, bstart, row_start, dinv, csr);

    // ---- GCN layer 1: stage = fp8(dinv*(X@W1)) [MFMA]; h1(bf16) = relu(gather*dinv + b1) ----
    gemm_mfma_kernel<128, 128, false><<<(NNODES + 63) / 64, 256, 0, stream>>>(X, Wt1, dinv, stage);
    gather128_kernel<<<(NNODES + 3) / 4, 256, 0, stream>>>(stage, row_start, csr, dinv, b1, h1);

    // ---- GCN layer 2: stage = fp8(dinv*(h1@W2)) [MFMA]; h2 = gather*dinv + b2 ----
    gemm_mfma_kernel<128, 64, true><<<(NNODES + 63) / 64, 256, 0, stream>>>(h1, Wt2, dinv, stage);
    gather64_kernel<<<(NNODES + 3) / 4, 256, 0, stream>>>(stage, row_start, csr, dinv, b2, h2);

    // ---- fused attention + pooling ----
    attnpool_kernel<<<512, 256, 0, stream>>>(h2, Wf1, bf1, Wf2, bf2, geacc, ata, colsum);
    final_kernel<<<1, 64, 0, stream>>>(geacc, ata, colsum, Wl, bl, out);
}

// Round 7
// 401.329 us; speedup vs baseline: 1.2873x; 1.2631x over previous
//
#include <hip/hip_runtime.h>
#include <hip/hip_bf16.h>
#include <math.h>

#define NNODES 100000
#define NEDGES 3200000
#define NBUK ((NNODES + 127) >> 7)   // 782 buckets of 128 nodes
#define NCHUNK 256
#define EPC (NEDGES / NCHUNK)        // 12500 edges per chunk
#define NPAD 100352
#define SLICEB ((size_t)NPAD * 32)   // layer-2 slice: 32 B/node = 3.2 MB (fits 4MB XCD L2)

typedef float floatx2 __attribute__((ext_vector_type(2)));
typedef float f32x4 __attribute__((ext_vector_type(4)));
typedef short bf16x8 __attribute__((ext_vector_type(8)));

// ---- bf16 pack/unpack ----
__device__ __forceinline__ unsigned short f2bf(float x) {
    unsigned u = __float_as_uint(x);
    unsigned r = u + 0x7FFFu + ((u >> 16) & 1u);
    return (unsigned short)(r >> 16);
}

// ---- fp8 e4m3 packed accumulate (gfx950 HW converts) ----
__device__ __forceinline__ void acc8_fp8(uint2 v, floatx2* a) {
    a[0] += __builtin_amdgcn_cvt_pk_f32_fp8(v.x, false);
    a[1] += __builtin_amdgcn_cvt_pk_f32_fp8(v.x, true);
    a[2] += __builtin_amdgcn_cvt_pk_f32_fp8(v.y, false);
    a[3] += __builtin_amdgcn_cvt_pk_f32_fp8(v.y, true);
}

// ---------------- weight prep: Wt1[n][k]=bf16(W1[k][n]); Wt2[n][k]=bf16(W2[k][n]) ----------------
__global__ void prep_w_kernel(const float* __restrict__ W1, const float* __restrict__ W2,
                              unsigned short* __restrict__ Wt1, unsigned short* __restrict__ Wt2) {
    int i = blockIdx.x * 256 + threadIdx.x;
    if (i < 128 * 128) {
        int k = i >> 7, n = i & 127;        // coalesced read over n
        Wt1[n * 128 + k] = f2bf(W1[i]);
    } else if (i < 128 * 128 + 128 * 64) {
        int j = i - 128 * 128;
        int k = j >> 6, n = j & 63;
        Wt2[n * 128 + k] = f2bf(W2[j]);
    }
}

// ---------------- pass 1: per-chunk bucket histogram (LDS, int4 reads) ----------------
__global__ __launch_bounds__(1024) void chunk_hist_kernel(const int* __restrict__ dst,
                                                          int* __restrict__ hist) {
    __shared__ int h[NBUK];
    int c = blockIdx.x, t = threadIdx.x;
    for (int i = t; i < NBUK; i += 1024) h[i] = 0;
    __syncthreads();
    const int4* d4 = (const int4*)(dst + c * EPC);
    for (int i = t; i < EPC / 4; i += 1024) {
        int4 d = d4[i];
        atomicAdd(&h[d.x >> 7], 1);
        atomicAdd(&h[d.y >> 7], 1);
        atomicAdd(&h[d.z >> 7], 1);
        atomicAdd(&h[d.w >> 7], 1);
    }
    __syncthreads();
    for (int i = t; i < NBUK; i += 1024)
        hist[c * NBUK + i] = h[i];
}

// ---------------- pass 2: per-bucket exclusive prefix over chunks (parallel: 1 block/bucket) ----
__global__ __launch_bounds__(256) void col_scan_kernel(int* __restrict__ hist,
                                                       int* __restrict__ btot) {
    __shared__ int sdat[NCHUNK];
    int b = blockIdx.x;          // bucket
    int t = threadIdx.x;         // chunk (NCHUNK == 256 == blockDim)
    int v = hist[t * NBUK + b];
    sdat[t] = v;
    __syncthreads();
#pragma unroll
    for (int off = 1; off < NCHUNK; off <<= 1) {
        int x = (t >= off) ? sdat[t - off] : 0;
        __syncthreads();
        sdat[t] += x;
        __syncthreads();
    }
    hist[t * NBUK + b] = sdat[t] - v;     // exclusive prefix over chunks
    if (t == NCHUNK - 1) btot[b] = sdat[t];
}

// ---------------- pass 3: scan bucket totals -> bstart; zero small accumulators ----------------
__global__ void bucket_scan_kernel(const int* __restrict__ btot, int* __restrict__ bstart,
                                   int* __restrict__ row_start, float* __restrict__ smalls) {
    __shared__ int s[1024];
    int t = threadIdx.x;
    if (t < 592) smalls[t] = 0.0f;   // colsum(8) ata(64) ge(512)
    int v = (t < NBUK) ? btot[t] : 0;
    s[t] = v;
    __syncthreads();
    for (int off = 1; off < 1024; off <<= 1) {
        int x = (t >= off) ? s[t - off] : 0;
        __syncthreads();
        s[t] += x;
        __syncthreads();
    }
    if (t < NBUK) bstart[t] = s[t] - v;
    if (t == 0) {
        bstart[NBUK] = NEDGES;
        row_start[NNODES] = NEDGES;
    }
}

// ---------------- pass 4: deterministic scatter into bucket order (LDS cursors, int4 reads) ----
__global__ __launch_bounds__(1024) void chunk_scatter_kernel(const int* __restrict__ src,
                                                             const int* __restrict__ dst,
                                                             const int* __restrict__ hist,
                                                             const int* __restrict__ bstart,
                                                             int* __restrict__ ebuk) {
    __shared__ int cur[NBUK];
    int c = blockIdx.x, t = threadIdx.x;
    for (int i = t; i < NBUK; i += 1024)
        cur[i] = bstart[i] + hist[c * NBUK + i];
    __syncthreads();
    const int4* s4 = (const int4*)(src + c * EPC);
    const int4* d4 = (const int4*)(dst + c * EPC);
    for (int i = t; i < EPC / 4; i += 1024) {
        int4 s = s4[i];
        int4 d = d4[i];
        int p0 = atomicAdd(&cur[d.x >> 7], 1);
        ebuk[p0] = s.x | ((d.x & 127) << 20);
        int p1 = atomicAdd(&cur[d.y >> 7], 1);
        ebuk[p1] = s.y | ((d.y & 127) << 20);
        int p2 = atomicAdd(&cur[d.z >> 7], 1);
        ebuk[p2] = s.z | ((d.z & 127) << 20);
        int p3 = atomicAdd(&cur[d.w >> 7], 1);
        ebuk[p3] = s.w | ((d.w & 127) << 20);
    }
}

// ---------------- per-bucket: node counts, row_start, dinv, csr fill ----------------
__global__ __launch_bounds__(256) void build_kernel(const int* __restrict__ ebuk,
                                                    const int* __restrict__ bstart,
                                                    int* __restrict__ row_start,
                                                    float* __restrict__ dinv,
                                                    int* __restrict__ csr) {
    __shared__ int cnt[128];
    __shared__ int scn[128];
    __shared__ int cur[128];
    int b = blockIdx.x;
    int t = threadIdx.x;
    int s0 = bstart[b], s1 = bstart[b + 1];
    if (t < 128) cnt[t] = 0;
    __syncthreads();
    for (int i = s0 + t; i < s1; i += 256)
        atomicAdd(&cnt[(ebuk[i] >> 20) & 127], 1);
    __syncthreads();
    if (t < 128) scn[t] = cnt[t];
    __syncthreads();
#pragma unroll
    for (int off = 1; off < 128; off <<= 1) {
        int x = (t < 128 && t >= off) ? scn[t - off] : 0;
        __syncthreads();
        if (t < 128) scn[t] += x;
        __syncthreads();
    }
    int node = b * 128 + t;
    if (t < 128) {
        int rs = s0 + scn[t] - cnt[t];
        cur[t] = rs;
        if (node < NNODES) {
            row_start[node] = rs;
            dinv[node] = rsqrtf((float)cnt[t] + 1.0f);
        }
    }
    __syncthreads();
    for (int i = s0 + t; i < s1; i += 256) {
        int v = ebuk[i];
        int pos = atomicAdd(&cur[(v >> 20) & 127], 1);
        csr[pos] = v & 0xFFFFF;
    }
}

// ---------------- MFMA GEMM: stage(fp8) = rowscale * (A @ W) ----------------
// A: fp32 (ABF16=false) or bf16 (true), [N,KIN]; Wt: bf16 transposed [KOUT][KIN].
// 256 threads = 4 waves; 64-row tile; wave w handles rows w*16..w*16+15, all KOUT cols.
// KOUT=128: row-major store (layer-1 gather is line-optimal on 128-B rows).
// KOUT=64:  slice-major store (2 x 32-B slices of 3.2 MB, parity-XCD pinned gather).
template <int KIN, int KOUT, bool ABF16>
__global__ __launch_bounds__(256) void gemm_mfma_kernel(const void* __restrict__ Av,
                                                        const unsigned short* __restrict__ Wt,
                                                        const float* __restrict__ rowscale,
                                                        unsigned char* __restrict__ stage) {
    constexpr int LDK = KIN + 8;          // bf16 elems; 16 B pad
    constexpr int LDC = KOUT + 4;         // fp32 elems
    constexpr int SH_AB = (64 + KOUT) * LDK * 2;
    constexpr int SH_C  = 64 * LDC * 4;
    constexpr int SH = SH_AB > SH_C ? SH_AB : SH_C;
    __shared__ char shbuf[SH];
    unsigned short* As = (unsigned short*)shbuf;       // [64][LDK]
    unsigned short* Ws = As + 64 * LDK;                // [KOUT][LDK]
    float* Cs = (float*)shbuf;                         // [64][LDC] (aliases, used after)
    int t = threadIdx.x;
    int block_row = blockIdx.x * 64;

    // stage Wt -> LDS (bf16, already transposed)
    for (int idx = t; idx < KOUT * (KIN / 8); idx += 256) {
        int n = idx / (KIN / 8), c = idx % (KIN / 8);
        *(uint4*)(Ws + n * LDK + c * 8) = *(const uint4*)(Wt + n * KIN + c * 8);
    }
    // stage A -> LDS (convert to bf16 if fp32)
    if (ABF16) {
        const unsigned short* A = (const unsigned short*)Av;
        for (int idx = t; idx < 64 * (KIN / 8); idx += 256) {
            int r = idx / (KIN / 8), c = idx % (KIN / 8);
            uint4 v = make_uint4(0, 0, 0, 0);
            if (block_row + r < NNODES)
                v = *(const uint4*)(A + (size_t)(block_row + r) * KIN + c * 8);
            *(uint4*)(As + r * LDK + c * 8) = v;
        }
    } else {
        const float* A = (const float*)Av;
        for (int idx = t; idx < 64 * (KIN / 4); idx += 256) {
            int r = idx / (KIN / 4), c = idx % (KIN / 4);
            float4 v = make_float4(0.f, 0.f, 0.f, 0.f);
            if (block_row + r < NNODES)
                v = *(const float4*)(A + (size_t)(block_row + r) * KIN + c * 4);
            unsigned p0 = (unsigned)f2bf(v.x) | ((unsigned)f2bf(v.y) << 16);
            unsigned p1 = (unsigned)f2bf(v.z) | ((unsigned)f2bf(v.w) << 16);
            *(uint2*)(As + r * LDK + c * 4) = make_uint2(p0, p1);
        }
    }
    __syncthreads();

    int wv = t >> 6, lane = t & 63;
    int r0 = wv * 16;
    int m = lane & 15, q = lane >> 4;     // A[m][k=q*8+j]; B[k=q*8+j][n=m]; C: col=m,row=q*4+reg
    constexpr int NT = KOUT / 16;
    constexpr int KS = KIN / 32;
    f32x4 acc[NT];
#pragma unroll
    for (int nt = 0; nt < NT; nt++) acc[nt] = (f32x4)(0.f);
    bf16x8 afr[KS];
#pragma unroll
    for (int ks = 0; ks < KS; ks++)
        afr[ks] = *(bf16x8*)(As + (r0 + m) * LDK + ks * 32 + q * 8);
#pragma unroll
    for (int nt = 0; nt < NT; nt++) {
#pragma unroll
        for (int ks = 0; ks < KS; ks++) {
            bf16x8 b = *(bf16x8*)(Ws + (nt * 16 + m) * LDK + ks * 32 + q * 8);
            acc[nt] = __builtin_amdgcn_mfma_f32_16x16x32_bf16(afr[ks], b, acc[nt], 0, 0, 0);
        }
    }
    __syncthreads();
    // C -> LDS (C/D layout: col=lane&15, row=(lane>>4)*4+reg)
#pragma unroll
    for (int nt = 0; nt < NT; nt++)
#pragma unroll
        for (int j = 0; j < 4; j++)
            Cs[(r0 + q * 4 + j) * LDC + nt * 16 + m] = acc[nt][j];
    __syncthreads();
    // epilogue: scale by dinv, fp8 pack, store
    for (int idx = t; idx < 64 * (KOUT / 4); idx += 256) {
        int r = idx / (KOUT / 4), c4 = idx % (KOUT / 4);
        int row = block_row + r;
        if (row < NNODES) {
            float4 v = *(float4*)(Cs + r * LDC + c4 * 4);
            float d = rowscale[row];
            int pk = __builtin_amdgcn_cvt_pk_fp8_f32(v.x * d, v.y * d, 0, false);
            pk = __builtin_amdgcn_cvt_pk_fp8_f32(v.z * d, v.w * d, pk, true);
            if constexpr (KOUT == 64) {
                // slice s = c4>>3 (feature/32); 32-B node rows within slice
                *(unsigned*)(stage + (size_t)(c4 >> 3) * SLICEB
                                   + ((size_t)row << 5) + ((c4 & 7) << 2)) = (unsigned)pk;
            } else {
                *(unsigned*)(stage + (size_t)row * KOUT + c4 * 4) = (unsigned)pk;
            }
        }
    }
}

// ---------------- gather K=128 fp8: 4 groups x 16 lanes x 8 B; 64-edge windows ----------------
// Line-optimal: 16 lanes cover one full 128-B line per edge. (Proven 421-us config.)
__global__ __launch_bounds__(256) void gather128_kernel(
    const unsigned char* __restrict__ hs, const int* __restrict__ row_start,
    const int* __restrict__ csr, const float* __restrict__ dinv,
    const float* __restrict__ bias, unsigned short* __restrict__ out) {
    int wave = threadIdx.x >> 6;
    int lane = threadIdx.x & 63;
    int n = blockIdx.x * 4 + wave;
    if (n >= NNODES) return;
    int g = lane >> 4;          // 0..3: edge sub-group
    int c = lane & 15;          // uint2 index within 128 B row
    unsigned boff = (unsigned)c << 3;
    int start = row_start[n], end = row_start[n + 1];
    floatx2 acc[4];
#pragma unroll
    for (int i = 0; i < 4; i++) acc[i] = (floatx2)(0.f);
    int w = (start + 3) & ~3;
    if (w > end) w = end;
    {   // head (<=3 edges): groups 0..2, one edge each
        int e2 = start + g;
        if (e2 < w) {
            unsigned o = ((unsigned)csr[e2] << 7) + boff;
            acc8_fp8(*(const uint2*)(hs + o), acc);
        }
    }
    // 64-edge windows: 4 groups x 16 contiguous edges, 16 gathers in flight per lane
    for (; w + 64 <= end; w += 64) {
        const int* cp = csr + w + 16 * g;
        int4 ca = *(const int4*)(cp);
        int4 cb = *(const int4*)(cp + 4);
        int4 cc = *(const int4*)(cp + 8);
        int4 cd = *(const int4*)(cp + 12);
        uint2 v0  = *(const uint2*)(hs + (((unsigned)ca.x << 7) + boff));
        uint2 v1  = *(const uint2*)(hs + (((unsigned)ca.y << 7) + boff));
        uint2 v2  = *(const uint2*)(hs + (((unsigned)ca.z << 7) + boff));
        uint2 v3  = *(const uint2*)(hs + (((unsigned)ca.w << 7) + boff));
        uint2 v4  = *(const uint2*)(hs + (((unsigned)cb.x << 7) + boff));
        uint2 v5  = *(const uint2*)(hs + (((unsigned)cb.y << 7) + boff));
        uint2 v6  = *(const uint2*)(hs + (((unsigned)cb.z << 7) + boff));
        uint2 v7  = *(const uint2*)(hs + (((unsigned)cb.w << 7) + boff));
        uint2 v8  = *(const uint2*)(hs + (((unsigned)cc.x << 7) + boff));
        uint2 v9  = *(const uint2*)(hs + (((unsigned)cc.y << 7) + boff));
        uint2 v10 = *(const uint2*)(hs + (((unsigned)cc.z << 7) + boff));
        uint2 v11 = *(const uint2*)(hs + (((unsigned)cc.w << 7) + boff));
        uint2 v12 = *(const uint2*)(hs + (((unsigned)cd.x << 7) + boff));
        uint2 v13 = *(const uint2*)(hs + (((unsigned)cd.y << 7) + boff));
        uint2 v14 = *(const uint2*)(hs + (((unsigned)cd.z << 7) + boff));
        uint2 v15 = *(const uint2*)(hs + (((unsigned)cd.w << 7) + boff));
        acc8_fp8(v0, acc);  acc8_fp8(v1, acc);  acc8_fp8(v2, acc);  acc8_fp8(v3, acc);
        acc8_fp8(v4, acc);  acc8_fp8(v5, acc);  acc8_fp8(v6, acc);  acc8_fp8(v7, acc);
        acc8_fp8(v8, acc);  acc8_fp8(v9, acc);  acc8_fp8(v10, acc); acc8_fp8(v11, acc);
        acc8_fp8(v12, acc); acc8_fp8(v13, acc); acc8_fp8(v14, acc); acc8_fp8(v15, acc);
    }
    // 16-edge windows
    for (; w + 16 <= end; w += 16) {
        int4 cs = *(const int4*)(csr + w + 4 * g);
        uint2 v0 = *(const uint2*)(hs + (((unsigned)cs.x << 7) + boff));
        uint2 v1 = *(const uint2*)(hs + (((unsigned)cs.y << 7) + boff));
        uint2 v2 = *(const uint2*)(hs + (((unsigned)cs.z << 7) + boff));
        uint2 v3 = *(const uint2*)(hs + (((unsigned)cs.w << 7) + boff));
        acc8_fp8(v0, acc); acc8_fp8(v1, acc); acc8_fp8(v2, acc); acc8_fp8(v3, acc);
    }
    for (int e2 = w + g; e2 < end; e2 += 4) {
        unsigned o = ((unsigned)csr[e2] << 7) + boff;
        acc8_fp8(*(const uint2*)(hs + o), acc);
    }
#pragma unroll
    for (int off = 16; off <= 32; off <<= 1)
#pragma unroll
        for (int i = 0; i < 4; i++) {
            acc[i].x += __shfl_xor(acc[i].x, off);
            acc[i].y += __shfl_xor(acc[i].y, off);
        }
    if (g == 0) {
        floatx2 s[4];
#pragma unroll
        for (int i = 0; i < 4; i++) s[i] = (floatx2)(0.f);
        acc8_fp8(*(const uint2*)(hs + (((unsigned)n << 7) + boff)), s);
        float d = dinv[n];
        int j = c * 8;
        float4 b0 = *(const float4*)(bias + j);
        float4 b1 = *(const float4*)(bias + j + 4);
        float r0 = fmaxf((acc[0].x + s[0].x) * d + b0.x, 0.f);
        float r1 = fmaxf((acc[0].y + s[0].y) * d + b0.y, 0.f);
        float r2 = fmaxf((acc[1].x + s[1].x) * d + b0.z, 0.f);
        float r3 = fmaxf((acc[1].y + s[1].y) * d + b0.w, 0.f);
        float r4 = fmaxf((acc[2].x + s[2].x) * d + b1.x, 0.f);
        float r5 = fmaxf((acc[2].y + s[2].y) * d + b1.y, 0.f);
        float r6 = fmaxf((acc[3].x + s[3].x) * d + b1.z, 0.f);
        float r7 = fmaxf((acc[3].y + s[3].y) * d + b1.w, 0.f);
        uint4 p;
        p.x = (unsigned)f2bf(r0) | ((unsigned)f2bf(r1) << 16);
        p.y = (unsigned)f2bf(r2) | ((unsigned)f2bf(r3) << 16);
        p.z = (unsigned)f2bf(r4) | ((unsigned)f2bf(r5) << 16);
        p.w = (unsigned)f2bf(r6) | ((unsigned)f2bf(r7) << 16);
        *(uint4*)(out + (((size_t)n << 7) + j)) = p;
    }
}

// ---------------- layer-2 sliced gather: 4 nodes/wave x 1 slice(32B), slice pinned to XCD ------
// grid = (NNODES/16) * 2; slice = blockIdx % 2 (round-robin dispatch -> per-XCD-parity slice
// residency: 3.2 MB fits the 4 MB XCD L2). Lane split: gn=lane>>4 (node), es=(lane>>2)&3
// (edge slot), c=lane&3 (8B of slice). Verified structure+numerics from round 3.
template <int S, bool L1OUT>
__global__ __launch_bounds__(256) void gather_slice_kernel(
    const unsigned char* __restrict__ hs, const int* __restrict__ row_start,
    const int* __restrict__ csr, const float* __restrict__ dinv,
    const float* __restrict__ bias, void* __restrict__ outv) {
    int t = threadIdx.x;
    int wave = t >> 6, lane = t & 63;
    int s = (int)(blockIdx.x % S);
    int nb = (int)(blockIdx.x / S);
    int gn = lane >> 4, es = (lane >> 2) & 3, c = lane & 3;
    int node = nb * 16 + wave * 4 + gn;      // (NNODES/16)*16 == NNODES exactly
    const unsigned char* hss = hs + (size_t)s * SLICEB;
    unsigned boff = (unsigned)c << 3;
    int start = row_start[node], end = row_start[node + 1];
    floatx2 acc[4];
#pragma unroll
    for (int i = 0; i < 4; i++) acc[i] = (floatx2)(0.f);
    int e = start + es;
    // main: 8 csr loads + 8 gathers in flight per lane (one batch covers deg<=32)
    for (; e + 28 < end; e += 32) {
        int i0 = csr[e];      int i1 = csr[e + 4];
        int i2 = csr[e + 8];  int i3 = csr[e + 12];
        int i4 = csr[e + 16]; int i5 = csr[e + 20];
        int i6 = csr[e + 24]; int i7 = csr[e + 28];
        uint2 v0 = *(const uint2*)(hss + (((unsigned)i0 << 5) + boff));
        uint2 v1 = *(const uint2*)(hss + (((unsigned)i1 << 5) + boff));
        uint2 v2 = *(const uint2*)(hss + (((unsigned)i2 << 5) + boff));
        uint2 v3 = *(const uint2*)(hss + (((unsigned)i3 << 5) + boff));
        uint2 v4 = *(const uint2*)(hss + (((unsigned)i4 << 5) + boff));
        uint2 v5 = *(const uint2*)(hss + (((unsigned)i5 << 5) + boff));
        uint2 v6 = *(const uint2*)(hss + (((unsigned)i6 << 5) + boff));
        uint2 v7 = *(const uint2*)(hss + (((unsigned)i7 << 5) + boff));
        acc8_fp8(v0, acc); acc8_fp8(v1, acc); acc8_fp8(v2, acc); acc8_fp8(v3, acc);
        acc8_fp8(v4, acc); acc8_fp8(v5, acc); acc8_fp8(v6, acc); acc8_fp8(v7, acc);
    }
    // mid: 2 in flight
    for (; e + 4 < end; e += 8) {
        int i0 = csr[e];
        int i1 = csr[e + 4];
        uint2 v0 = *(const uint2*)(hss + (((unsigned)i0 << 5) + boff));
        uint2 v1 = *(const uint2*)(hss + (((unsigned)i1 << 5) + boff));
        acc8_fp8(v0, acc); acc8_fp8(v1, acc);
    }
    if (e < end) {
        uint2 v = *(const uint2*)(hss + (((unsigned)csr[e] << 5) + boff));
        acc8_fp8(v, acc);
    }
    // reduce across 4 edge-slots (lane bits 2-3)
#pragma unroll
    for (int off = 4; off <= 8; off <<= 1)
#pragma unroll
        for (int i = 0; i < 4; i++) {
            acc[i].x += __shfl_xor(acc[i].x, off);
            acc[i].y += __shfl_xor(acc[i].y, off);
        }
    if (es == 0) {
        floatx2 sf[4];
#pragma unroll
        for (int i = 0; i < 4; i++) sf[i] = (floatx2)(0.f);
        acc8_fp8(*(const uint2*)(hss + (((unsigned)node << 5) + boff)), sf);
        float d = dinv[node];
        int j = s * 32 + c * 8;
        float4 b0 = *(const float4*)(bias + j);
        float4 b1 = *(const float4*)(bias + j + 4);
        float r0 = (acc[0].x + sf[0].x) * d + b0.x;
        float r1 = (acc[0].y + sf[0].y) * d + b0.y;
        float r2 = (acc[1].x + sf[1].x) * d + b0.z;
        float r3 = (acc[1].y + sf[1].y) * d + b0.w;
        float r4 = (acc[2].x + sf[2].x) * d + b1.x;
        float r5 = (acc[2].y + sf[2].y) * d + b1.y;
        float r6 = (acc[3].x + sf[3].x) * d + b1.z;
        float r7 = (acc[3].y + sf[3].y) * d + b1.w;
        if (L1OUT) {
            r0 = fmaxf(r0, 0.f); r1 = fmaxf(r1, 0.f);
            r2 = fmaxf(r2, 0.f); r3 = fmaxf(r3, 0.f);
            r4 = fmaxf(r4, 0.f); r5 = fmaxf(r5, 0.f);
            r6 = fmaxf(r6, 0.f); r7 = fmaxf(r7, 0.f);
            uint4 p;
            p.x = (unsigned)f2bf(r0) | ((unsigned)f2bf(r1) << 16);
            p.y = (unsigned)f2bf(r2) | ((unsigned)f2bf(r3) << 16);
            p.z = (unsigned)f2bf(r4) | ((unsigned)f2bf(r5) << 16);
            p.w = (unsigned)f2bf(r6) | ((unsigned)f2bf(r7) << 16);
            *(uint4*)((unsigned short*)outv + ((size_t)node << 7) + j) = p;
        } else {
            float* op = (float*)outv + ((size_t)node << 6) + j;
            *(float4*)op = make_float4(r0, r1, r2, r3);
            *(float4*)(op + 4) = make_float4(r4, r5, r6, r7);
        }
    }
}

// ---------------- fused attention + pooling (grid-stride over 64-row tiles) ----------------
__global__ __launch_bounds__(256) void attnpool_kernel(const float* __restrict__ h2,
                                                       const float* __restrict__ Wf1,
                                                       const float* __restrict__ bf1,
                                                       const float* __restrict__ Wf2,
                                                       const float* __restrict__ bf2,
                                                       float* __restrict__ ge,
                                                       float* __restrict__ ata,
                                                       float* __restrict__ colsum) {
    __shared__ float h2S[64][68];
    __shared__ float a1S[64][68];
    __shared__ float attS[64][8];
    __shared__ float colS[8][64];
    int t = threadIdx.x;
    int d0 = t >> 6;
    int j  = t & 63;
    int de = t >> 3, ee = t & 7;
    float accge0 = 0.f, accge1 = 0.f, accata = 0.f, acccol = 0.f;
    int ntiles = (NNODES + 63) / 64;
    for (int tile = blockIdx.x; tile < ntiles; tile += gridDim.x) {
        int base = tile * 64;
#pragma unroll
        for (int q = 0; q < 4; q++) {
            int idx = t + q * 256;
            int r = idx >> 4, cc = (idx & 15) * 4;
            int row = base + r;
            float4 v = (row < NNODES) ? *(const float4*)(h2 + (size_t)row * 64 + cc)
                                      : make_float4(0.f, 0.f, 0.f, 0.f);
            *(float4*)(&h2S[r][cc]) = v;
        }
        __syncthreads();
        {
            int cg = t & 15, rg = t >> 4;
            int jj = cg * 4, r0 = rg * 4;
            float4 b4 = *(const float4*)(bf1 + jj);
            float4 acc[4];
#pragma unroll
            for (int r = 0; r < 4; r++) acc[r] = b4;
#pragma unroll 4
            for (int k = 0; k < 64; k++) {
                float4 wv = *(const float4*)(Wf1 + (size_t)k * 64 + jj);
#pragma unroll
                for (int r = 0; r < 4; r++) {
                    float a = h2S[r0 + r][k];
                    acc[r].x += a * wv.x; acc[r].y += a * wv.y;
                    acc[r].z += a * wv.z; acc[r].w += a * wv.w;
                }
            }
#pragma unroll
            for (int r = 0; r < 4; r++) {
                a1S[r0 + r][jj]     = tanhf(acc[r].x);
                a1S[r0 + r][jj + 1] = tanhf(acc[r].y);
                a1S[r0 + r][jj + 2] = tanhf(acc[r].z);
                a1S[r0 + r][jj + 3] = tanhf(acc[r].w);
            }
        }
        __syncthreads();
        {
            int cc = t & 7, r = t >> 3;
#pragma unroll
            for (int h = 0; h < 2; h++) {
                int rr = r + h * 32;
                float acc = bf2[cc];
                for (int k = 0; k < 64; k++)
                    acc += a1S[rr][k] * Wf2[(size_t)k * 8 + cc];
                float ev = (base + rr < NNODES) ? __expf(acc) : 0.f;
                attS[rr][cc] = ev;
                colS[cc][rr] = ev;
            }
        }
        __syncthreads();
#pragma unroll 8
        for (int i = 0; i < 64; i++) {
            float hv = h2S[i][j];
            accge0 += attS[i][d0] * hv;
            accge1 += attS[i][d0 + 4] * hv;
        }
        if (t < 64) {
#pragma unroll 8
            for (int i = 0; i < 64; i++) accata += attS[i][de] * attS[i][ee];
        }
        if (t < 8) {
            float s = 0.f;
#pragma unroll
            for (int r = 0; r < 64; r++) s += colS[t][r];
            acccol += s;
        }
        __syncthreads();
    }
    atomicAdd(ge + d0 * 64 + j, accge0);
    atomicAdd(ge + (d0 + 4) * 64 + j, accge1);
    if (t < 64) atomicAdd(ata + de * 8 + ee, accata);
    if (t < 8) atomicAdd(colsum + t, acccol);
}

// ---------------- tiny epilogue ----------------
__global__ void final_kernel(const float* __restrict__ geacc, const float* __restrict__ ata,
                             const float* __restrict__ colsum, const float* __restrict__ Wl,
                             const float* __restrict__ bl, float* __restrict__ out) {
    __shared__ float geF[512];
    __shared__ float inv[8];
    __shared__ float logits[10];
    int t = threadIdx.x;
    if (t < 8) inv[t] = 1.0f / colsum[t];
    __syncthreads();
    for (int idx = t; idx < 512; idx += 64) {
        int d = idx >> 6;
        float v = geacc[idx] * inv[d];
        geF[idx] = v;
        out[idx] = v;                       // graph_embedding
    }
    __syncthreads();
    if (t == 0) {
        float pen = 0.f;
        for (int d = 0; d < 8; d++) {
            float s = 0.f;
            for (int e = 0; e < 8; e++) {
                float p = ata[d * 8 + e] * inv[d] * inv[e] - (d == e ? 1.0f : 0.0f);
                s += p * p;
            }
            pen += sqrtf(s);
        }
        out[512] = pen;                     // penalty
    }
    if (t < 10) {
        float acc = bl[t];
        for (int k = 0; k < 512; k++) acc += geF[k] * Wl[(size_t)k * 10 + t];
        logits[t] = acc;
    }
    __syncthreads();
    if (t == 0) {
        float m = -INFINITY;
        for (int l = 0; l < 10; l++) m = fmaxf(m, logits[l]);
        float s = 0.f;
        for (int l = 0; l < 10; l++) s += expf(logits[l] - m);
        float ls = logf(s);
        for (int l = 0; l < 10; l++) out[513 + l] = logits[l] - m - ls;  // log_softmax
    }
}

extern "C" void kernel_launch(void* const* d_in, const int* in_sizes, int n_in,
                              void* d_out, int out_size, void* d_ws, size_t ws_size,
                              hipStream_t stream) {
    const int* esrc = (const int*)d_in[0];
    const int* edst = esrc + NEDGES;
    const float* X   = (const float*)d_in[1];
    const float* W1  = (const float*)d_in[2];
    const float* b1  = (const float*)d_in[3];
    const float* W2  = (const float*)d_in[4];
    const float* b2  = (const float*)d_in[5];
    const float* Wf1 = (const float*)d_in[6];
    const float* bf1 = (const float*)d_in[7];
    const float* Wf2 = (const float*)d_in[8];
    const float* bf2 = (const float*)d_in[9];
    const float* Wl  = (const float*)d_in[10];
    const float* bl  = (const float*)d_in[11];
    float* out = (float*)d_out;

    // workspace layout
    float* ws     = (float*)d_ws;
    float* dinv   = ws;                               // N (padded to 100352)
    float* smalls = ws + 100352;                      // 1024
    float* colsum = smalls + 8;                       // 8
    float* ata    = smalls + 16;                      // 64
    float* geacc  = smalls + 80;                      // 512
    float* A = ws + 101376;                           // N*128 fp32 region
    float* B = A + (size_t)NNODES * 128;              // N*128 fp32 region
    int* row_start = (int*)(B + (size_t)NNODES * 128);// N+1 (padded 100352)
    int* btot      = row_start + 100352;              // NBUK (padded 1024)
    int* bstart    = btot + 1024;                     // NBUK+1 (padded 1024)
    int* csr       = bstart + 1024;                   // E
    unsigned short* Wt1 = (unsigned short*)(csr + NEDGES);  // 128*128 bf16
    unsigned short* Wt2 = Wt1 + 128 * 128;                  // 64*128 bf16
    int* ebuk      = (int*)A;                         // E temp (consumed before gemm1 writes A)
    int* hist      = (int*)B;                         // NCHUNK*NBUK temp (consumed before gather writes B)
    unsigned char* stage = (unsigned char*)A;         // fp8 staging (N*128 row-major, or 2*SLICEB)
    unsigned short* h1 = (unsigned short*)B;          // N*128 bf16
    float* h2  = B;                                   // N*64 fp32 (overwrites h1 after gemm2 consumed it)

    // ---- weight prep (bf16, transposed) ----
    prep_w_kernel<<<96, 256, 0, stream>>>(W1, W2, Wt1, Wt2);

    // ---- CSR build + dinv (deterministic two-pass counting sort) ----
    chunk_hist_kernel<<<NCHUNK, 1024, 0, stream>>>(edst, hist);
    col_scan_kernel<<<NBUK, 256, 0, stream>>>(hist, btot);
    bucket_scan_kernel<<<1, 1024, 0, stream>>>(btot, bstart, row_start, smalls);
    chunk_scatter_kernel<<<NCHUNK, 1024, 0, stream>>>(esrc, edst, hist, bstart, ebuk);
    build_kernel<<<NBUK, 256, 0, stream>>>(ebuk, bstart, row_start, dinv, csr);

    // ---- GCN layer 1: stage = fp8(dinv*(X@W1)) row-major [MFMA]; h1(bf16)=relu(gather*dinv+b1) ----
    gemm_mfma_kernel<128, 128, false><<<(NNODES + 63) / 64, 256, 0, stream>>>(X, Wt1, dinv, stage);
    gather128_kernel<<<(NNODES + 3) / 4, 256, 0, stream>>>(stage, row_start, csr, dinv, b1, h1);

    // ---- GCN layer 2: stage = fp8 2x32B-slices of dinv*(h1@W2) [MFMA]; h2 = gather*dinv + b2 ----
    gemm_mfma_kernel<128, 64, true><<<(NNODES + 63) / 64, 256, 0, stream>>>(h1, Wt2, dinv, stage);
    gather_slice_kernel<2, false><<<(NNODES / 16) * 2, 256, 0, stream>>>(stage, row_start, csr, dinv, b2, h2);

    // ---- fused attention + pooling ----
    attnpool_kernel<<<512, 256, 0, stream>>>(h2, Wf1, bf1, Wf2, bf2, geacc, ata, colsum);
    final_kernel<<<1, 64, 0, stream>>>(geacc, ata, colsum, Wl, bl, out);
}

// Round 8
// 398.810 us; speedup vs baseline: 1.2955x; 1.0063x over previous
//
#include <hip/hip_runtime.h>
#include <hip/hip_bf16.h>
#include <math.h>

#define NNODES 100000
#define NEDGES 3200000
#define NBUK ((NNODES + 127) >> 7)   // 782 buckets of 128 nodes
#define NCHUNK 256
#define EPC (NEDGES / NCHUNK)        // 12500 edges per chunk
#define NPAD 100352
#define SLICEB ((size_t)NPAD * 32)   // layer-2 slice: 32 B/node = 3.2 MB (fits 4MB XCD L2)

typedef float floatx2 __attribute__((ext_vector_type(2)));
typedef float f32x4 __attribute__((ext_vector_type(4)));
typedef short bf16x8 __attribute__((ext_vector_type(8)));

// ---- bf16 pack/unpack ----
__device__ __forceinline__ unsigned short f2bf(float x) {
    unsigned u = __float_as_uint(x);
    unsigned r = u + 0x7FFFu + ((u >> 16) & 1u);
    return (unsigned short)(r >> 16);
}

// ---- fp8 e4m3 packed accumulate (gfx950 HW converts) ----
__device__ __forceinline__ void acc8_fp8(uint2 v, floatx2* a) {
    a[0] += __builtin_amdgcn_cvt_pk_f32_fp8(v.x, false);
    a[1] += __builtin_amdgcn_cvt_pk_f32_fp8(v.x, true);
    a[2] += __builtin_amdgcn_cvt_pk_f32_fp8(v.y, false);
    a[3] += __builtin_amdgcn_cvt_pk_f32_fp8(v.y, true);
}

// ---------------- pass 1 + weight prep merged ----------------
// blocks < NCHUNK: per-chunk bucket histogram (LDS, int4 reads).
// blocks >= NCHUNK (24 blocks x 1024 threads = 24576 = 128*128 + 128*64 exactly):
//   Wt1[n][k]=bf16(W1[k][n]); Wt2[n][k]=bf16(W2[k][n]).
__global__ __launch_bounds__(1024) void chunk_hist_kernel(const int* __restrict__ dst,
                                                          int* __restrict__ hist,
                                                          const float* __restrict__ W1,
                                                          const float* __restrict__ W2,
                                                          unsigned short* __restrict__ Wt1,
                                                          unsigned short* __restrict__ Wt2) {
    __shared__ int h[NBUK];
    int c = blockIdx.x, t = threadIdx.x;
    if (c >= NCHUNK) {
        int i = (c - NCHUNK) * 1024 + t;
        if (i < 128 * 128) {
            int k = i >> 7, n = i & 127;        // coalesced read over n
            Wt1[n * 128 + k] = f2bf(W1[i]);
        } else {
            int j = i - 128 * 128;
            int k = j >> 6, n = j & 63;
            Wt2[n * 128 + k] = f2bf(W2[j]);
        }
        return;
    }
    for (int i = t; i < NBUK; i += 1024) h[i] = 0;
    __syncthreads();
    const int4* d4 = (const int4*)(dst + c * EPC);
    for (int i = t; i < EPC / 4; i += 1024) {
        int4 d = d4[i];
        atomicAdd(&h[d.x >> 7], 1);
        atomicAdd(&h[d.y >> 7], 1);
        atomicAdd(&h[d.z >> 7], 1);
        atomicAdd(&h[d.w >> 7], 1);
    }
    __syncthreads();
    for (int i = t; i < NBUK; i += 1024)
        hist[c * NBUK + i] = h[i];
}

// ---------------- pass 2: per-bucket exclusive prefix over chunks (parallel: 1 block/bucket) ----
__global__ __launch_bounds__(256) void col_scan_kernel(int* __restrict__ hist,
                                                       int* __restrict__ btot) {
    __shared__ int sdat[NCHUNK];
    int b = blockIdx.x;          // bucket
    int t = threadIdx.x;         // chunk (NCHUNK == 256 == blockDim)
    int v = hist[t * NBUK + b];
    sdat[t] = v;
    __syncthreads();
#pragma unroll
    for (int off = 1; off < NCHUNK; off <<= 1) {
        int x = (t >= off) ? sdat[t - off] : 0;
        __syncthreads();
        sdat[t] += x;
        __syncthreads();
    }
    hist[t * NBUK + b] = sdat[t] - v;     // exclusive prefix over chunks
    if (t == NCHUNK - 1) btot[b] = sdat[t];
}

// ---------------- pass 3: scan bucket totals -> bstart; zero small accumulators ----------------
__global__ void bucket_scan_kernel(const int* __restrict__ btot, int* __restrict__ bstart,
                                   int* __restrict__ row_start, float* __restrict__ smalls) {
    __shared__ int s[1024];
    int t = threadIdx.x;
    if (t < 592) smalls[t] = 0.0f;   // colsum(8) ata(64) ge(512)
    int v = (t < NBUK) ? btot[t] : 0;
    s[t] = v;
    __syncthreads();
    for (int off = 1; off < 1024; off <<= 1) {
        int x = (t >= off) ? s[t - off] : 0;
        __syncthreads();
        s[t] += x;
        __syncthreads();
    }
    if (t < NBUK) bstart[t] = s[t] - v;
    if (t == 0) {
        bstart[NBUK] = NEDGES;
        row_start[NNODES] = NEDGES;
    }
}

// ---------------- pass 4: deterministic scatter into bucket order (LDS cursors, int4 reads) ----
__global__ __launch_bounds__(1024) void chunk_scatter_kernel(const int* __restrict__ src,
                                                             const int* __restrict__ dst,
                                                             const int* __restrict__ hist,
                                                             const int* __restrict__ bstart,
                                                             int* __restrict__ ebuk) {
    __shared__ int cur[NBUK];
    int c = blockIdx.x, t = threadIdx.x;
    for (int i = t; i < NBUK; i += 1024)
        cur[i] = bstart[i] + hist[c * NBUK + i];
    __syncthreads();
    const int4* s4 = (const int4*)(src + c * EPC);
    const int4* d4 = (const int4*)(dst + c * EPC);
    for (int i = t; i < EPC / 4; i += 1024) {
        int4 s = s4[i];
        int4 d = d4[i];
        int p0 = atomicAdd(&cur[d.x >> 7], 1);
        ebuk[p0] = s.x | ((d.x & 127) << 20);
        int p1 = atomicAdd(&cur[d.y >> 7], 1);
        ebuk[p1] = s.y | ((d.y & 127) << 20);
        int p2 = atomicAdd(&cur[d.z >> 7], 1);
        ebuk[p2] = s.z | ((d.z & 127) << 20);
        int p3 = atomicAdd(&cur[d.w >> 7], 1);
        ebuk[p3] = s.w | ((d.w & 127) << 20);
    }
}

// ---------------- per-bucket: node counts, row_start, dinv, csr fill ----------------
__global__ __launch_bounds__(256) void build_kernel(const int* __restrict__ ebuk,
                                                    const int* __restrict__ bstart,
                                                    int* __restrict__ row_start,
                                                    float* __restrict__ dinv,
                                                    int* __restrict__ csr) {
    __shared__ int cnt[128];
    __shared__ int scn[128];
    __shared__ int cur[128];
    int b = blockIdx.x;
    int t = threadIdx.x;
    int s0 = bstart[b], s1 = bstart[b + 1];
    if (t < 128) cnt[t] = 0;
    __syncthreads();
    for (int i = s0 + t; i < s1; i += 256)
        atomicAdd(&cnt[(ebuk[i] >> 20) & 127], 1);
    __syncthreads();
    if (t < 128) scn[t] = cnt[t];
    __syncthreads();
#pragma unroll
    for (int off = 1; off < 128; off <<= 1) {
        int x = (t < 128 && t >= off) ? scn[t - off] : 0;
        __syncthreads();
        if (t < 128) scn[t] += x;
        __syncthreads();
    }
    int node = b * 128 + t;
    if (t < 128) {
        int rs = s0 + scn[t] - cnt[t];
        cur[t] = rs;
        if (node < NNODES) {
            row_start[node] = rs;
            dinv[node] = rsqrtf((float)cnt[t] + 1.0f);
        }
    }
    __syncthreads();
    for (int i = s0 + t; i < s1; i += 256) {
        int v = ebuk[i];
        int pos = atomicAdd(&cur[(v >> 20) & 127], 1);
        csr[pos] = v & 0xFFFFF;
    }
}

// ---------------- MFMA GEMM: stage(fp8) = rowscale * (A @ W) ----------------
// A: fp32 (ABF16=false) or bf16 (true), [N,KIN]; Wt: bf16 transposed [KOUT][KIN].
// 512 threads = 8 waves; 128-row tile; wave w handles rows w*16..w*16+15, all KOUT cols.
// (Per-wave math identical to the verified 64-row/4-wave version; 2x W-stage amortization,
//  higher occupancy: gemm1 16 waves/CU, gemm2 24 waves/CU.)
// KOUT=128: row-major store (layer-1 gather is line-optimal on 128-B rows).
// KOUT=64:  slice-major store (2 x 32-B slices of 3.2 MB, parity-XCD pinned gather).
template <int KIN, int KOUT, bool ABF16>
__global__ __launch_bounds__(512) void gemm_mfma_kernel(const void* __restrict__ Av,
                                                        const unsigned short* __restrict__ Wt,
                                                        const float* __restrict__ rowscale,
                                                        unsigned char* __restrict__ stage) {
    constexpr int ROWS = 128;
    constexpr int LDK = KIN + 8;          // bf16 elems; 16 B pad
    constexpr int LDC = KOUT + 4;         // fp32 elems
    constexpr int SH_AB = (ROWS + KOUT) * LDK * 2;
    constexpr int SH_C  = ROWS * LDC * 4;
    constexpr int SH = SH_AB > SH_C ? SH_AB : SH_C;
    __shared__ char shbuf[SH];
    unsigned short* As = (unsigned short*)shbuf;       // [ROWS][LDK]
    unsigned short* Ws = As + ROWS * LDK;              // [KOUT][LDK]
    float* Cs = (float*)shbuf;                         // [ROWS][LDC] (aliases, used after)
    int t = threadIdx.x;
    int block_row = blockIdx.x * ROWS;

    // stage Wt -> LDS (bf16, already transposed)
    for (int idx = t; idx < KOUT * (KIN / 8); idx += 512) {
        int n = idx / (KIN / 8), c = idx % (KIN / 8);
        *(uint4*)(Ws + n * LDK + c * 8) = *(const uint4*)(Wt + n * KIN + c * 8);
    }
    // stage A -> LDS (convert to bf16 if fp32)
    if (ABF16) {
        const unsigned short* A = (const unsigned short*)Av;
        for (int idx = t; idx < ROWS * (KIN / 8); idx += 512) {
            int r = idx / (KIN / 8), c = idx % (KIN / 8);
            uint4 v = make_uint4(0, 0, 0, 0);
            if (block_row + r < NNODES)
                v = *(const uint4*)(A + (size_t)(block_row + r) * KIN + c * 8);
            *(uint4*)(As + r * LDK + c * 8) = v;
        }
    } else {
        const float* A = (const float*)Av;
        for (int idx = t; idx < ROWS * (KIN / 4); idx += 512) {
            int r = idx / (KIN / 4), c = idx % (KIN / 4);
            float4 v = make_float4(0.f, 0.f, 0.f, 0.f);
            if (block_row + r < NNODES)
                v = *(const float4*)(A + (size_t)(block_row + r) * KIN + c * 4);
            unsigned p0 = (unsigned)f2bf(v.x) | ((unsigned)f2bf(v.y) << 16);
            unsigned p1 = (unsigned)f2bf(v.z) | ((unsigned)f2bf(v.w) << 16);
            *(uint2*)(As + r * LDK + c * 4) = make_uint2(p0, p1);
        }
    }
    __syncthreads();

    int wv = t >> 6, lane = t & 63;
    int r0 = wv * 16;                     // 8 waves x 16 rows = 128 rows
    int m = lane & 15, q = lane >> 4;     // A[m][k=q*8+j]; B[k=q*8+j][n=m]; C: col=m,row=q*4+reg
    constexpr int NT = KOUT / 16;
    constexpr int KS = KIN / 32;
    f32x4 acc[NT];
#pragma unroll
    for (int nt = 0; nt < NT; nt++) acc[nt] = (f32x4)(0.f);
    bf16x8 afr[KS];
#pragma unroll
    for (int ks = 0; ks < KS; ks++)
        afr[ks] = *(bf16x8*)(As + (r0 + m) * LDK + ks * 32 + q * 8);
#pragma unroll
    for (int nt = 0; nt < NT; nt++) {
#pragma unroll
        for (int ks = 0; ks < KS; ks++) {
            bf16x8 b = *(bf16x8*)(Ws + (nt * 16 + m) * LDK + ks * 32 + q * 8);
            acc[nt] = __builtin_amdgcn_mfma_f32_16x16x32_bf16(afr[ks], b, acc[nt], 0, 0, 0);
        }
    }
    __syncthreads();
    // C -> LDS (C/D layout: col=lane&15, row=(lane>>4)*4+reg)
#pragma unroll
    for (int nt = 0; nt < NT; nt++)
#pragma unroll
        for (int j = 0; j < 4; j++)
            Cs[(r0 + q * 4 + j) * LDC + nt * 16 + m] = acc[nt][j];
    __syncthreads();
    // epilogue: scale by dinv, fp8 pack, store
    for (int idx = t; idx < ROWS * (KOUT / 4); idx += 512) {
        int r = idx / (KOUT / 4), c4 = idx % (KOUT / 4);
        int row = block_row + r;
        if (row < NNODES) {
            float4 v = *(float4*)(Cs + r * LDC + c4 * 4);
            float d = rowscale[row];
            int pk = __builtin_amdgcn_cvt_pk_fp8_f32(v.x * d, v.y * d, 0, false);
            pk = __builtin_amdgcn_cvt_pk_fp8_f32(v.z * d, v.w * d, pk, true);
            if constexpr (KOUT == 64) {
                // slice s = c4>>3 (feature/32); 32-B node rows within slice
                *(unsigned*)(stage + (size_t)(c4 >> 3) * SLICEB
                                   + ((size_t)row << 5) + ((c4 & 7) << 2)) = (unsigned)pk;
            } else {
                *(unsigned*)(stage + (size_t)row * KOUT + c4 * 4) = (unsigned)pk;
            }
        }
    }
}

// ---------------- gather K=128 fp8: 4 groups x 16 lanes x 8 B; 64-edge windows ----------------
// Line-optimal: 16 lanes cover one full 128-B line per edge. (Proven config — UNCHANGED.)
__global__ __launch_bounds__(256) void gather128_kernel(
    const unsigned char* __restrict__ hs, const int* __restrict__ row_start,
    const int* __restrict__ csr, const float* __restrict__ dinv,
    const float* __restrict__ bias, unsigned short* __restrict__ out) {
    int wave = threadIdx.x >> 6;
    int lane = threadIdx.x & 63;
    int n = blockIdx.x * 4 + wave;
    if (n >= NNODES) return;
    int g = lane >> 4;          // 0..3: edge sub-group
    int c = lane & 15;          // uint2 index within 128 B row
    unsigned boff = (unsigned)c << 3;
    int start = row_start[n], end = row_start[n + 1];
    floatx2 acc[4];
#pragma unroll
    for (int i = 0; i < 4; i++) acc[i] = (floatx2)(0.f);
    int w = (start + 3) & ~3;
    if (w > end) w = end;
    {   // head (<=3 edges): groups 0..2, one edge each
        int e2 = start + g;
        if (e2 < w) {
            unsigned o = ((unsigned)csr[e2] << 7) + boff;
            acc8_fp8(*(const uint2*)(hs + o), acc);
        }
    }
    // 64-edge windows: 4 groups x 16 contiguous edges, 16 gathers in flight per lane
    for (; w + 64 <= end; w += 64) {
        const int* cp = csr + w + 16 * g;
        int4 ca = *(const int4*)(cp);
        int4 cb = *(const int4*)(cp + 4);
        int4 cc = *(const int4*)(cp + 8);
        int4 cd = *(const int4*)(cp + 12);
        uint2 v0  = *(const uint2*)(hs + (((unsigned)ca.x << 7) + boff));
        uint2 v1  = *(const uint2*)(hs + (((unsigned)ca.y << 7) + boff));
        uint2 v2  = *(const uint2*)(hs + (((unsigned)ca.z << 7) + boff));
        uint2 v3  = *(const uint2*)(hs + (((unsigned)ca.w << 7) + boff));
        uint2 v4  = *(const uint2*)(hs + (((unsigned)cb.x << 7) + boff));
        uint2 v5  = *(const uint2*)(hs + (((unsigned)cb.y << 7) + boff));
        uint2 v6  = *(const uint2*)(hs + (((unsigned)cb.z << 7) + boff));
        uint2 v7  = *(const uint2*)(hs + (((unsigned)cb.w << 7) + boff));
        uint2 v8  = *(const uint2*)(hs + (((unsigned)cc.x << 7) + boff));
        uint2 v9  = *(const uint2*)(hs + (((unsigned)cc.y << 7) + boff));
        uint2 v10 = *(const uint2*)(hs + (((unsigned)cc.z << 7) + boff));
        uint2 v11 = *(const uint2*)(hs + (((unsigned)cc.w << 7) + boff));
        uint2 v12 = *(const uint2*)(hs + (((unsigned)cd.x << 7) + boff));
        uint2 v13 = *(const uint2*)(hs + (((unsigned)cd.y << 7) + boff));
        uint2 v14 = *(const uint2*)(hs + (((unsigned)cd.z << 7) + boff));
        uint2 v15 = *(const uint2*)(hs + (((unsigned)cd.w << 7) + boff));
        acc8_fp8(v0, acc);  acc8_fp8(v1, acc);  acc8_fp8(v2, acc);  acc8_fp8(v3, acc);
        acc8_fp8(v4, acc);  acc8_fp8(v5, acc);  acc8_fp8(v6, acc);  acc8_fp8(v7, acc);
        acc8_fp8(v8, acc);  acc8_fp8(v9, acc);  acc8_fp8(v10, acc); acc8_fp8(v11, acc);
        acc8_fp8(v12, acc); acc8_fp8(v13, acc); acc8_fp8(v14, acc); acc8_fp8(v15, acc);
    }
    // 16-edge windows
    for (; w + 16 <= end; w += 16) {
        int4 cs = *(const int4*)(csr + w + 4 * g);
        uint2 v0 = *(const uint2*)(hs + (((unsigned)cs.x << 7) + boff));
        uint2 v1 = *(const uint2*)(hs + (((unsigned)cs.y << 7) + boff));
        uint2 v2 = *(const uint2*)(hs + (((unsigned)cs.z << 7) + boff));
        uint2 v3 = *(const uint2*)(hs + (((unsigned)cs.w << 7) + boff));
        acc8_fp8(v0, acc); acc8_fp8(v1, acc); acc8_fp8(v2, acc); acc8_fp8(v3, acc);
    }
    for (int e2 = w + g; e2 < end; e2 += 4) {
        unsigned o = ((unsigned)csr[e2] << 7) + boff;
        acc8_fp8(*(const uint2*)(hs + o), acc);
    }
#pragma unroll
    for (int off = 16; off <= 32; off <<= 1)
#pragma unroll
        for (int i = 0; i < 4; i++) {
            acc[i].x += __shfl_xor(acc[i].x, off);
            acc[i].y += __shfl_xor(acc[i].y, off);
        }
    if (g == 0) {
        floatx2 s[4];
#pragma unroll
        for (int i = 0; i < 4; i++) s[i] = (floatx2)(0.f);
        acc8_fp8(*(const uint2*)(hs + (((unsigned)n << 7) + boff)), s);
        float d = dinv[n];
        int j = c * 8;
        float4 b0 = *(const float4*)(bias + j);
        float4 b1 = *(const float4*)(bias + j + 4);
        float r0 = fmaxf((acc[0].x + s[0].x) * d + b0.x, 0.f);
        float r1 = fmaxf((acc[0].y + s[0].y) * d + b0.y, 0.f);
        float r2 = fmaxf((acc[1].x + s[1].x) * d + b0.z, 0.f);
        float r3 = fmaxf((acc[1].y + s[1].y) * d + b0.w, 0.f);
        float r4 = fmaxf((acc[2].x + s[2].x) * d + b1.x, 0.f);
        float r5 = fmaxf((acc[2].y + s[2].y) * d + b1.y, 0.f);
        float r6 = fmaxf((acc[3].x + s[3].x) * d + b1.z, 0.f);
        float r7 = fmaxf((acc[3].y + s[3].y) * d + b1.w, 0.f);
        uint4 p;
        p.x = (unsigned)f2bf(r0) | ((unsigned)f2bf(r1) << 16);
        p.y = (unsigned)f2bf(r2) | ((unsigned)f2bf(r3) << 16);
        p.z = (unsigned)f2bf(r4) | ((unsigned)f2bf(r5) << 16);
        p.w = (unsigned)f2bf(r6) | ((unsigned)f2bf(r7) << 16);
        *(uint4*)(out + (((size_t)n << 7) + j)) = p;
    }
}

// ---------------- layer-2 sliced gather: 4 nodes/wave x 1 slice(32B), slice pinned to XCD ------
// (Proven config — UNCHANGED.)
template <int S, bool L1OUT>
__global__ __launch_bounds__(256) void gather_slice_kernel(
    const unsigned char* __restrict__ hs, const int* __restrict__ row_start,
    const int* __restrict__ csr, const float* __restrict__ dinv,
    const float* __restrict__ bias, void* __restrict__ outv) {
    int t = threadIdx.x;
    int wave = t >> 6, lane = t & 63;
    int s = (int)(blockIdx.x % S);
    int nb = (int)(blockIdx.x / S);
    int gn = lane >> 4, es = (lane >> 2) & 3, c = lane & 3;
    int node = nb * 16 + wave * 4 + gn;      // (NNODES/16)*16 == NNODES exactly
    const unsigned char* hss = hs + (size_t)s * SLICEB;
    unsigned boff = (unsigned)c << 3;
    int start = row_start[node], end = row_start[node + 1];
    floatx2 acc[4];
#pragma unroll
    for (int i = 0; i < 4; i++) acc[i] = (floatx2)(0.f);
    int e = start + es;
    // main: 8 csr loads + 8 gathers in flight per lane (one batch covers deg<=32)
    for (; e + 28 < end; e += 32) {
        int i0 = csr[e];      int i1 = csr[e + 4];
        int i2 = csr[e + 8];  int i3 = csr[e + 12];
        int i4 = csr[e + 16]; int i5 = csr[e + 20];
        int i6 = csr[e + 24]; int i7 = csr[e + 28];
        uint2 v0 = *(const uint2*)(hss + (((unsigned)i0 << 5) + boff));
        uint2 v1 = *(const uint2*)(hss + (((unsigned)i1 << 5) + boff));
        uint2 v2 = *(const uint2*)(hss + (((unsigned)i2 << 5) + boff));
        uint2 v3 = *(const uint2*)(hss + (((unsigned)i3 << 5) + boff));
        uint2 v4 = *(const uint2*)(hss + (((unsigned)i4 << 5) + boff));
        uint2 v5 = *(const uint2*)(hss + (((unsigned)i5 << 5) + boff));
        uint2 v6 = *(const uint2*)(hss + (((unsigned)i6 << 5) + boff));
        uint2 v7 = *(const uint2*)(hss + (((unsigned)i7 << 5) + boff));
        acc8_fp8(v0, acc); acc8_fp8(v1, acc); acc8_fp8(v2, acc); acc8_fp8(v3, acc);
        acc8_fp8(v4, acc); acc8_fp8(v5, acc); acc8_fp8(v6, acc); acc8_fp8(v7, acc);
    }
    // mid: 2 in flight
    for (; e + 4 < end; e += 8) {
        int i0 = csr[e];
        int i1 = csr[e + 4];
        uint2 v0 = *(const uint2*)(hss + (((unsigned)i0 << 5) + boff));
        uint2 v1 = *(const uint2*)(hss + (((unsigned)i1 << 5) + boff));
        acc8_fp8(v0, acc); acc8_fp8(v1, acc);
    }
    if (e < end) {
        uint2 v = *(const uint2*)(hss + (((unsigned)csr[e] << 5) + boff));
        acc8_fp8(v, acc);
    }
    // reduce across 4 edge-slots (lane bits 2-3)
#pragma unroll
    for (int off = 4; off <= 8; off <<= 1)
#pragma unroll
        for (int i = 0; i < 4; i++) {
            acc[i].x += __shfl_xor(acc[i].x, off);
            acc[i].y += __shfl_xor(acc[i].y, off);
        }
    if (es == 0) {
        floatx2 sf[4];
#pragma unroll
        for (int i = 0; i < 4; i++) sf[i] = (floatx2)(0.f);
        acc8_fp8(*(const uint2*)(hss + (((unsigned)node << 5) + boff)), sf);
        float d = dinv[node];
        int j = s * 32 + c * 8;
        float4 b0 = *(const float4*)(bias + j);
        float4 b1 = *(const float4*)(bias + j + 4);
        float r0 = (acc[0].x + sf[0].x) * d + b0.x;
        float r1 = (acc[0].y + sf[0].y) * d + b0.y;
        float r2 = (acc[1].x + sf[1].x) * d + b0.z;
        float r3 = (acc[1].y + sf[1].y) * d + b0.w;
        float r4 = (acc[2].x + sf[2].x) * d + b1.x;
        float r5 = (acc[2].y + sf[2].y) * d + b1.y;
        float r6 = (acc[3].x + sf[3].x) * d + b1.z;
        float r7 = (acc[3].y + sf[3].y) * d + b1.w;
        if (L1OUT) {
            r0 = fmaxf(r0, 0.f); r1 = fmaxf(r1, 0.f);
            r2 = fmaxf(r2, 0.f); r3 = fmaxf(r3, 0.f);
            r4 = fmaxf(r4, 0.f); r5 = fmaxf(r5, 0.f);
            r6 = fmaxf(r6, 0.f); r7 = fmaxf(r7, 0.f);
            uint4 p;
            p.x = (unsigned)f2bf(r0) | ((unsigned)f2bf(r1) << 16);
            p.y = (unsigned)f2bf(r2) | ((unsigned)f2bf(r3) << 16);
            p.z = (unsigned)f2bf(r4) | ((unsigned)f2bf(r5) << 16);
            p.w = (unsigned)f2bf(r6) | ((unsigned)f2bf(r7) << 16);
            *(uint4*)((unsigned short*)outv + ((size_t)node << 7) + j) = p;
        } else {
            float* op = (float*)outv + ((size_t)node << 6) + j;
            *(float4*)op = make_float4(r0, r1, r2, r3);
            *(float4*)(op + 4) = make_float4(r4, r5, r6, r7);
        }
    }
}

// ---------------- fused attention + pooling (grid-stride over 64-row tiles) ----------------
__global__ __launch_bounds__(256) void attnpool_kernel(const float* __restrict__ h2,
                                                       const float* __restrict__ Wf1,
                                                       const float* __restrict__ bf1,
                                                       const float* __restrict__ Wf2,
                                                       const float* __restrict__ bf2,
                                                       float* __restrict__ ge,
                                                       float* __restrict__ ata,
                                                       float* __restrict__ colsum) {
    __shared__ float h2S[64][68];
    __shared__ float a1S[64][68];
    __shared__ float attS[64][8];
    __shared__ float colS[8][64];
    int t = threadIdx.x;
    int d0 = t >> 6;
    int j  = t & 63;
    int de = t >> 3, ee = t & 7;
    float accge0 = 0.f, accge1 = 0.f, accata = 0.f, acccol = 0.f;
    int ntiles = (NNODES + 63) / 64;
    for (int tile = blockIdx.x; tile < ntiles; tile += gridDim.x) {
        int base = tile * 64;
#pragma unroll
        for (int q = 0; q < 4; q++) {
            int idx = t + q * 256;
            int r = idx >> 4, cc = (idx & 15) * 4;
            int row = base + r;
            float4 v = (row < NNODES) ? *(const float4*)(h2 + (size_t)row * 64 + cc)
                                      : make_float4(0.f, 0.f, 0.f, 0.f);
            *(float4*)(&h2S[r][cc]) = v;
        }
        __syncthreads();
        {
            int cg = t & 15, rg = t >> 4;
            int jj = cg * 4, r0 = rg * 4;
            float4 b4 = *(const float4*)(bf1 + jj);
            float4 acc[4];
#pragma unroll
            for (int r = 0; r < 4; r++) acc[r] = b4;
#pragma unroll 4
            for (int k = 0; k < 64; k++) {
                float4 wv = *(const float4*)(Wf1 + (size_t)k * 64 + jj);
#pragma unroll
                for (int r = 0; r < 4; r++) {
                    float a = h2S[r0 + r][k];
                    acc[r].x += a * wv.x; acc[r].y += a * wv.y;
                    acc[r].z += a * wv.z; acc[r].w += a * wv.w;
                }
            }
#pragma unroll
            for (int r = 0; r < 4; r++) {
                a1S[r0 + r][jj]     = tanhf(acc[r].x);
                a1S[r0 + r][jj + 1] = tanhf(acc[r].y);
                a1S[r0 + r][jj + 2] = tanhf(acc[r].z);
                a1S[r0 + r][jj + 3] = tanhf(acc[r].w);
            }
        }
        __syncthreads();
        {
            int cc = t & 7, r = t >> 3;
#pragma unroll
            for (int h = 0; h < 2; h++) {
                int rr = r + h * 32;
                float acc = bf2[cc];
                for (int k = 0; k < 64; k++)
                    acc += a1S[rr][k] * Wf2[(size_t)k * 8 + cc];
                float ev = (base + rr < NNODES) ? __expf(acc) : 0.f;
                attS[rr][cc] = ev;
                colS[cc][rr] = ev;
            }
        }
        __syncthreads();
#pragma unroll 8
        for (int i = 0; i < 64; i++) {
            float hv = h2S[i][j];
            accge0 += attS[i][d0] * hv;
            accge1 += attS[i][d0 + 4] * hv;
        }
        if (t < 64) {
#pragma unroll 8
            for (int i = 0; i < 64; i++) accata += attS[i][de] * attS[i][ee];
        }
        if (t < 8) {
            float s = 0.f;
#pragma unroll
            for (int r = 0; r < 64; r++) s += colS[t][r];
            acccol += s;
        }
        __syncthreads();
    }
    atomicAdd(ge + d0 * 64 + j, accge0);
    atomicAdd(ge + (d0 + 4) * 64 + j, accge1);
    if (t < 64) atomicAdd(ata + de * 8 + ee, accata);
    if (t < 8) atomicAdd(colsum + t, acccol);
}

// ---------------- tiny epilogue ----------------
__global__ void final_kernel(const float* __restrict__ geacc, const float* __restrict__ ata,
                             const float* __restrict__ colsum, const float* __restrict__ Wl,
                             const float* __restrict__ bl, float* __restrict__ out) {
    __shared__ float geF[512];
    __shared__ float inv[8];
    __shared__ float logits[10];
    int t = threadIdx.x;
    if (t < 8) inv[t] = 1.0f / colsum[t];
    __syncthreads();
    for (int idx = t; idx < 512; idx += 64) {
        int d = idx >> 6;
        float v = geacc[idx] * inv[d];
        geF[idx] = v;
        out[idx] = v;                       // graph_embedding
    }
    __syncthreads();
    if (t == 0) {
        float pen = 0.f;
        for (int d = 0; d < 8; d++) {
            float s = 0.f;
            for (int e = 0; e < 8; e++) {
                float p = ata[d * 8 + e] * inv[d] * inv[e] - (d == e ? 1.0f : 0.0f);
                s += p * p;
            }
            pen += sqrtf(s);
        }
        out[512] = pen;                     // penalty
    }
    if (t < 10) {
        float acc = bl[t];
        for (int k = 0; k < 512; k++) acc += geF[k] * Wl[(size_t)k * 10 + t];
        logits[t] = acc;
    }
    __syncthreads();
    if (t == 0) {
        float m = -INFINITY;
        for (int l = 0; l < 10; l++) m = fmaxf(m, logits[l]);
        float s = 0.f;
        for (int l = 0; l < 10; l++) s += expf(logits[l] - m);
        float ls = logf(s);
        for (int l = 0; l < 10; l++) out[513 + l] = logits[l] - m - ls;  // log_softmax
    }
}

extern "C" void kernel_launch(void* const* d_in, const int* in_sizes, int n_in,
                              void* d_out, int out_size, void* d_ws, size_t ws_size,
                              hipStream_t stream) {
    const int* esrc = (const int*)d_in[0];
    const int* edst = esrc + NEDGES;
    const float* X   = (const float*)d_in[1];
    const float* W1  = (const float*)d_in[2];
    const float* b1  = (const float*)d_in[3];
    const float* W2  = (const float*)d_in[4];
    const float* b2  = (const float*)d_in[5];
    const float* Wf1 = (const float*)d_in[6];
    const float* bf1 = (const float*)d_in[7];
    const float* Wf2 = (const float*)d_in[8];
    const float* bf2 = (const float*)d_in[9];
    const float* Wl  = (const float*)d_in[10];
    const float* bl  = (const float*)d_in[11];
    float* out = (float*)d_out;

    // workspace layout
    float* ws     = (float*)d_ws;
    float* dinv   = ws;                               // N (padded to 100352)
    float* smalls = ws + 100352;                      // 1024
    float* colsum = smalls + 8;                       // 8
    float* ata    = smalls + 16;                      // 64
    float* geacc  = smalls + 80;                      // 512
    float* A = ws + 101376;                           // N*128 fp32 region
    float* B = A + (size_t)NNODES * 128;              // N*128 fp32 region
    int* row_start = (int*)(B + (size_t)NNODES * 128);// N+1 (padded 100352)
    int* btot      = row_start + 100352;              // NBUK (padded 1024)
    int* bstart    = btot + 1024;                     // NBUK+1 (padded 1024)
    int* csr       = bstart + 1024;                   // E
    unsigned short* Wt1 = (unsigned short*)(csr + NEDGES);  // 128*128 bf16
    unsigned short* Wt2 = Wt1 + 128 * 128;                  // 64*128 bf16
    int* ebuk      = (int*)A;                         // E temp (consumed before gemm1 writes A)
    int* hist      = (int*)B;                         // NCHUNK*NBUK temp (consumed before gather writes B)
    unsigned char* stage = (unsigned char*)A;         // fp8 staging (N*128 row-major, or 2*SLICEB)
    unsigned short* h1 = (unsigned short*)B;          // N*128 bf16
    float* h2  = B;                                   // N*64 fp32 (overwrites h1 after gemm2 consumed it)

    // ---- CSR build + dinv (deterministic two-pass counting sort); weight prep rides along ----
    chunk_hist_kernel<<<NCHUNK + 24, 1024, 0, stream>>>(edst, hist, W1, W2, Wt1, Wt2);
    col_scan_kernel<<<NBUK, 256, 0, stream>>>(hist, btot);
    bucket_scan_kernel<<<1, 1024, 0, stream>>>(btot, bstart, row_start, smalls);
    chunk_scatter_kernel<<<NCHUNK, 1024, 0, stream>>>(esrc, edst, hist, bstart, ebuk);
    build_kernel<<<NBUK, 256, 0, stream>>>(ebuk, bstart, row_start, dinv, csr);

    // ---- GCN layer 1: stage = fp8(dinv*(X@W1)) row-major [MFMA]; h1(bf16)=relu(gather*dinv+b1) ----
    gemm_mfma_kernel<128, 128, false><<<(NNODES + 127) / 128, 512, 0, stream>>>(X, Wt1, dinv, stage);
    gather128_kernel<<<(NNODES + 3) / 4, 256, 0, stream>>>(stage, row_start, csr, dinv, b1, h1);

    // ---- GCN layer 2: stage = fp8 2x32B-slices of dinv*(h1@W2) [MFMA]; h2 = gather*dinv + b2 ----
    gemm_mfma_kernel<128, 64, true><<<(NNODES + 127) / 128, 512, 0, stream>>>(h1, Wt2, dinv, stage);
    gather_slice_kernel<2, false><<<(NNODES / 16) * 2, 256, 0, stream>>>(stage, row_start, csr, dinv, b2, h2);

    // ---- fused attention + pooling ----
    attnpool_kernel<<<512, 256, 0, stream>>>(h2, Wf1, bf1, Wf2, bf2, geacc, ata, colsum);
    final_kernel<<<1, 64, 0, stream>>>(geacc, ata, colsum, Wl, bl, out);
}